// Round 1
// baseline (2019.998 us; speedup 1.0000x reference)
//
#include <hip/hip_runtime.h>
#include <cstddef>

#define HW 64
#define CIN 64
#define G4 256
#define TT 16
#define BB 2

__device__ __forceinline__ float hsig(float z) {
    return fminf(fmaxf(0.2f * z + 0.5f, 0.f), 1.f);
}

// Fused per-timestep conv: z = conv(x_t, Wx) + conv(h, Wh) + b
// Block: one (n, y, x-tile). 256 threads = 256 output channels.
template<int XT>
__global__ __launch_bounds__(256) void convstep_kernel(
    const float* __restrict__ xsrc,  // x + t*H*W*C; image n at + n*x_nstride
    size_t x_nstride,
    const float* __restrict__ hsrc,  // (B,H,W,F) fp32
    const float* __restrict__ Wx,    // (3,3,64,256)
    const float* __restrict__ Wh,    // (3,3,64,256)
    const float* __restrict__ bias,  // (256)
    float* __restrict__ zout)        // (B,H,W,256)
{
    constexpr int XTILES = HW / XT;
    const int bid = blockIdx.x;
    const int xt = bid % XTILES;
    const int y  = (bid / XTILES) % HW;
    const int n  = bid / (XTILES * HW);
    const int x0 = xt * XT;
    const int f  = threadIdx.x;   // output channel 0..255

    __shared__ float lx[3][XT + 2][CIN];
    __shared__ float lh[3][XT + 2][CIN];

    // Stage 3 input rows (y-1..y+1) x (x0-1..x0+XT) x 64ch for both inputs.
    const int total = 3 * (XT + 2) * CIN;
    for (int idx = threadIdx.x; idx < total; idx += 256) {
        const int cc = idx & (CIN - 1);
        const int xi = (idx >> 6) % (XT + 2);
        const int r  = idx / (CIN * (XT + 2));
        const int gy = y + r - 1;
        const int gx = x0 + xi - 1;
        float vx = 0.f, vh = 0.f;
        if (gy >= 0 && gy < HW && gx >= 0 && gx < HW) {
            const size_t po = ((size_t)gy * HW + gx) * CIN + cc;
            vx = xsrc[(size_t)n * x_nstride + po];
            vh = hsrc[(size_t)n * HW * HW * CIN + po];
        }
        lx[r][xi][cc] = vx;
        lh[r][xi][cc] = vh;
    }
    __syncthreads();

    float acc[XT];
    #pragma unroll
    for (int i = 0; i < XT; ++i) acc[i] = 0.f;

    #pragma unroll 1
    for (int s = 0; s < 2; ++s) {
        const float* __restrict__ w = s ? Wh : Wx;
        const float (*l)[XT + 2][CIN] = s ? lh : lx;
        #pragma unroll 1
        for (int ky = 0; ky < 3; ++ky) {
            #pragma unroll 1
            for (int c = 0; c < CIN; c += 2) {
                const float w00 = w[((ky * 3 + 0) * CIN + c    ) * G4 + f];
                const float w01 = w[((ky * 3 + 1) * CIN + c    ) * G4 + f];
                const float w02 = w[((ky * 3 + 2) * CIN + c    ) * G4 + f];
                const float w10 = w[((ky * 3 + 0) * CIN + c + 1) * G4 + f];
                const float w11 = w[((ky * 3 + 1) * CIN + c + 1) * G4 + f];
                const float w12 = w[((ky * 3 + 2) * CIN + c + 1) * G4 + f];
                #pragma unroll
                for (int xi = 0; xi < XT + 2; ++xi) {
                    const float2 v = *reinterpret_cast<const float2*>(&l[ky][xi][c]);
                    // v = in[x0+xi-1]; contributes to out xo = xi - kx
                    if (xi < XT)                  acc[xi]     += w00 * v.x + w10 * v.y;
                    if (xi >= 1 && xi - 1 < XT)   acc[xi - 1] += w01 * v.x + w11 * v.y;
                    if (xi >= 2)                  acc[xi - 2] += w02 * v.x + w12 * v.y;
                }
            }
        }
    }

    const float bv = bias[f];
    #pragma unroll
    for (int xo = 0; xo < XT; ++xo) {
        const size_t o = (((size_t)n * HW + y) * HW + (x0 + xo)) * G4 + f;
        zout[o] = acc[xo] + bv;
    }
}

// Elementwise gates + state update + BN-fused output write.
__global__ __launch_bounds__(256) void gate_kernel(
    const float* __restrict__ z,     // (B,H,W,256)
    float* __restrict__ cbuf,        // (B,H,W,64)
    float* __restrict__ hbuf,        // (B,H,W,64)
    float* __restrict__ out,         // (B,T,H,W,64)
    int t,
    const float* __restrict__ gamma, const float* __restrict__ beta,
    const float* __restrict__ mean,  const float* __restrict__ var)
{
    const int idx = blockIdx.x * 256 + threadIdx.x;   // over B*H*W*64
    const int fc  = idx & 63;
    const int pix = idx >> 6;                         // (b,y,x)
    const size_t zb = (size_t)pix * G4;
    const float zi = z[zb + fc];
    const float zf = z[zb + 64 + fc];
    const float zg = z[zb + 128 + fc];
    const float zo = z[zb + 192 + fc];
    const float ig = hsig(zi);
    const float fg = hsig(zf);
    const float gg = tanhf(zg);
    const float og = hsig(zo);
    const float c0 = cbuf[idx];
    const float cn = fg * c0 + ig * gg;
    const float hn = og * tanhf(cn);
    cbuf[idx] = cn;
    hbuf[idx] = hn;
    const float inv = gamma[fc] * rsqrtf(var[fc] + 1e-3f);
    const int b  = pix >> 12;        // 4096 pixels per batch image
    const int yx = pix & 4095;
    out[((size_t)(b * TT + t) * 4096 + yx) * 64 + fc] = hn * inv + (beta[fc] - mean[fc] * inv);
}

extern "C" void kernel_launch(void* const* d_in, const int* in_sizes, int n_in,
                              void* d_out, int out_size, void* d_ws, size_t ws_size,
                              hipStream_t stream) {
    const float* x     = (const float*)d_in[0];
    const float* Wx    = (const float*)d_in[1];
    const float* Wh    = (const float*)d_in[2];
    const float* b     = (const float*)d_in[3];
    const float* gamma = (const float*)d_in[4];
    const float* beta  = (const float*)d_in[5];
    const float* mean  = (const float*)d_in[6];
    const float* var   = (const float*)d_in[7];
    float* out = (float*)d_out;

    float* ws = (float*)d_ws;
    const size_t ZE = (size_t)BB * HW * HW * G4;   // 2,097,152 floats (8 MB)
    const size_t HE = (size_t)BB * HW * HW * 64;   //   524,288 floats (2 MB)
    float* zb = ws;
    float* hb = ws + ZE;
    float* cb = hb + HE;

    // h0 = c0 = 0 (hb, cb are contiguous)
    hipMemsetAsync(hb, 0, 2 * HE * sizeof(float), stream);

    constexpr int XT = 16;
    const int cblocks = BB * HW * (HW / XT);       // 512
    const int gblocks = (BB * HW * HW * 64) / 256; // 2048

    for (int t = 0; t < TT; ++t) {
        convstep_kernel<XT><<<cblocks, 256, 0, stream>>>(
            x + (size_t)t * HW * HW * CIN, (size_t)TT * HW * HW * CIN,
            hb, Wx, Wh, b, zb);
        gate_kernel<<<gblocks, 256, 0, stream>>>(
            zb, cb, hb, out, t, gamma, beta, mean, var);
    }
}

// Round 2
// 936.420 us; speedup vs baseline: 2.1571x; 2.1571x over previous
//
#include <hip/hip_runtime.h>
#include <cstddef>

typedef __attribute__((ext_vector_type(8))) short short8;
typedef __attribute__((ext_vector_type(4))) float f32x4;
typedef __attribute__((ext_vector_type(4))) unsigned short us4;

#define HW 64
#define TT 16

__device__ __forceinline__ unsigned short f2bf(float f) {
    unsigned u = __builtin_bit_cast(unsigned, f);
    u += 0x7fffu + ((u >> 16) & 1u);
    return (unsigned short)(u >> 16);
}
__device__ __forceinline__ float bf2f(unsigned short h) {
    unsigned u = ((unsigned)h) << 16;
    return __builtin_bit_cast(float, u);
}
__device__ __forceinline__ float hsig(float z) {
    return fminf(fmaxf(0.2f * z + 0.5f, 0.f), 1.f);
}

// One-time: transpose+split weights into Wb[n=256][k=2304] bf16 (hi/lo), BN fold.
// k layout: wslot(0=Wx_hi,1=Wx_lo,2=Wh_hi,3=Wh_lo)*576 + ((ky*3+kx)*64 + c)
__global__ __launch_bounds__(256) void prep_kernel(
    const float* __restrict__ Wx, const float* __restrict__ Wh,
    const float* __restrict__ gamma, const float* __restrict__ beta,
    const float* __restrict__ mean, const float* __restrict__ var,
    unsigned short* __restrict__ Wb, float* __restrict__ bn)
{
    const int bid = blockIdx.x;
    if (bid < 256) {
        const int n = bid;
        for (int k = threadIdx.x; k < 2304; k += 256) {
            const int wslot = k / 576;
            const int k5 = k % 576;
            const int c = k5 & 63;
            const int q = k5 >> 6;
            const int kx = q % 3;
            const int r = q / 3;
            const float* W = (wslot >> 1) ? Wh : Wx;
            const float v = W[(size_t)((r * 3 + kx) * 64 + c) * 256 + n];
            const unsigned short hi = f2bf(v);
            const unsigned short lo = f2bf(v - bf2f(hi));
            Wb[(size_t)n * 2304 + k] = (wslot & 1) ? lo : hi;
        }
    } else if (threadIdx.x < 64) {
        const int c = threadIdx.x;
        const float inv = gamma[c] * rsqrtf(var[c] + 1e-3f);
        bn[c] = inv;
        bn[64 + c] = beta[c] - mean[c] * inv;
    }
}

// Per-timestep fused: z = conv(x_t,Wx)+conv(h,Wh)+b via split-bf16 MFMA,
// then gates + state update + BN'd output, all in one kernel.
// Block = (n, y, xhalf): 32 pixels x 256 channels. 4 waves; wave w = gate w.
__global__ __launch_bounds__(256) void convstep_kernel(
    const float* __restrict__ x,             // (B,T,64,64,64) f32
    const unsigned short* __restrict__ hb_hi,// (B,4096,64) bf16  state in
    const unsigned short* __restrict__ hb_lo,
    const unsigned short* __restrict__ Wb,   // [256][2304] bf16
    const float* __restrict__ bias,          // [256]
    float* __restrict__ cbuf,                // (B,4096,64) f32
    unsigned short* __restrict__ ho_hi,      // state out (ping-pong)
    unsigned short* __restrict__ ho_lo,
    const float* __restrict__ bn,            // [128]: scale, shift
    float* __restrict__ out,                 // (B,T,64,64,64) f32
    const int t)
{
    const int bid = blockIdx.x;
    const int xh = bid & 1;
    const int y  = (bid >> 1) & 63;
    const int n  = bid >> 7;
    const int tid = threadIdx.x;

    // 4 tiles [3 rows][34 cols][72ch-pad] bf16 = 58752 B; overlaid by gate buf later
    __shared__ __align__(16) unsigned short smem[4 * 3 * 34 * 72];

    // ---- stage x_hi/x_lo/h_hi/h_lo tiles ----
    const float* __restrict__ xt = x + (size_t)(n * TT + t) * 4096 * 64;
    const size_t hbase = (size_t)n * 4096 * 64;

    for (int idx = tid; idx < 2 * 3 * 34 * 16; idx += 256) {
        const int cg  = idx & 15;           // group of 4 channels
        const int col = (idx >> 4) % 34;
        const int i3  = (idx >> 4) / 34;
        const int r   = i3 % 3;
        const int src = i3 / 3;             // 0=x, 1=h
        const int gy = y + r - 1;
        const int gx = xh * 32 + col - 1;
        const bool ok = ((unsigned)gy < 64u) && ((unsigned)gx < 64u);
        const int ebase = (r * 34 + col) * 72 + cg * 4;
        if (src == 0) {
            float4 v = make_float4(0.f, 0.f, 0.f, 0.f);
            if (ok) v = *(const float4*)(xt + (size_t)(gy * 64 + gx) * 64 + cg * 4);
            us4 hi, lo;
            hi.x = f2bf(v.x); lo.x = f2bf(v.x - bf2f(hi.x));
            hi.y = f2bf(v.y); lo.y = f2bf(v.y - bf2f(hi.y));
            hi.z = f2bf(v.z); lo.z = f2bf(v.z - bf2f(hi.z));
            hi.w = f2bf(v.w); lo.w = f2bf(v.w - bf2f(hi.w));
            *(us4*)&smem[0 * 7344 + ebase] = hi;
            *(us4*)&smem[1 * 7344 + ebase] = lo;
        } else {
            us4 hi = {0, 0, 0, 0}, lo = {0, 0, 0, 0};
            if (ok) {
                const size_t off = hbase + (size_t)(gy * 64 + gx) * 64 + cg * 4;
                hi = *(const us4*)(hb_hi + off);
                lo = *(const us4*)(hb_lo + off);
            }
            *(us4*)&smem[2 * 7344 + ebase] = hi;
            *(us4*)&smem[3 * 7344 + ebase] = lo;
        }
    }
    __syncthreads();

    // ---- K-loop: 6 half-convs x 18 k-steps of 32 ----
    const int lane = tid & 63;
    const int w  = tid >> 6;      // wave = gate
    const int p0 = lane & 15;
    const int g  = lane >> 4;

    const unsigned short* __restrict__ wl = Wb + (size_t)(w * 64 + p0) * 2304 + g * 8;
    const int eb0 = p0 * 72 + g * 8;
    const int eb1 = eb0 + 16 * 72;

    f32x4 acc[2][4] = {};

    constexpr int ASLOT[6] = {0, 1, 0, 2, 3, 2};   // xhi, xlo, xhi, hhi, hlo, hhi
    constexpr int WSLOT[6] = {0, 0, 1, 2, 2, 3};   // Wxh, Wxh, Wxl, Whh, Whh, Whl

    #pragma unroll
    for (int hc = 0; hc < 6; ++hc) {
        const int abase = ASLOT[hc] * 7344;
        const int wbase = WSLOT[hc] * 576;
        #pragma unroll
        for (int sub = 0; sub < 18; ++sub) {
            const int r  = sub / 6;
            const int kx = (sub / 2) % 3;
            const int cb = sub & 1;
            const int imm = abase + (r * 34 + kx) * 72 + cb * 32;
            const short8 a0 = *(const short8*)&smem[eb0 + imm];
            const short8 a1 = *(const short8*)&smem[eb1 + imm];
            #pragma unroll
            for (int nf = 0; nf < 4; ++nf) {
                const short8 b = *(const short8*)(wl + nf * 16 * 2304 + wbase + sub * 32);
                acc[0][nf] = __builtin_amdgcn_mfma_f32_16x16x32_bf16(a0, b, acc[0][nf], 0, 0, 0);
                acc[1][nf] = __builtin_amdgcn_mfma_f32_16x16x32_bf16(a1, b, acc[1][nf], 0, 0, 0);
            }
        }
    }

    // ---- activation -> LDS gate buffer (overlay smem) ----
    __syncthreads();                       // all waves done reading tiles
    float* gbuf = (float*)smem;            // [4][32][68] f32 = 34816 B

    float bv[4];
    #pragma unroll
    for (int nf = 0; nf < 4; ++nf) bv[nf] = bias[w * 64 + nf * 16 + p0];

    #pragma unroll
    for (int mf = 0; mf < 2; ++mf)
        #pragma unroll
        for (int nf = 0; nf < 4; ++nf)
            #pragma unroll
            for (int j = 0; j < 4; ++j) {
                float v = acc[mf][nf][j] + bv[nf];
                v = (w == 2) ? tanhf(v) : hsig(v);   // gate order i,f,g,o
                const int px = mf * 16 + g * 4 + j;
                gbuf[(w * 32 + px) * 68 + nf * 16 + p0] = v;
            }
    __syncthreads();

    // ---- state update + BN output: thread -> (pixel, 8 channels) ----
    const int p  = tid >> 3;
    const int c8 = (tid & 7) * 8;
    const float* g0 = &gbuf[(0 * 32 + p) * 68 + c8];
    const float* g1 = &gbuf[(1 * 32 + p) * 68 + c8];
    const float* g2 = &gbuf[(2 * 32 + p) * 68 + c8];
    const float* g3 = &gbuf[(3 * 32 + p) * 68 + c8];
    const size_t gpix = (size_t)((n * 64 + y) * 64 + xh * 32 + p);
    const size_t sb = gpix * 64 + c8;

    float iv[8], fv[8], gv[8], ov[8], cold[8], sc[8], sh[8];
    *(float4*)&iv[0] = *(const float4*)g0;       *(float4*)&iv[4] = *(const float4*)(g0 + 4);
    *(float4*)&fv[0] = *(const float4*)g1;       *(float4*)&fv[4] = *(const float4*)(g1 + 4);
    *(float4*)&gv[0] = *(const float4*)g2;       *(float4*)&gv[4] = *(const float4*)(g2 + 4);
    *(float4*)&ov[0] = *(const float4*)g3;       *(float4*)&ov[4] = *(const float4*)(g3 + 4);
    *(float4*)&cold[0] = *(const float4*)&cbuf[sb];      *(float4*)&cold[4] = *(const float4*)&cbuf[sb + 4];
    *(float4*)&sc[0] = *(const float4*)&bn[c8];          *(float4*)&sc[4] = *(const float4*)&bn[c8 + 4];
    *(float4*)&sh[0] = *(const float4*)&bn[64 + c8];     *(float4*)&sh[4] = *(const float4*)&bn[64 + c8 + 4];

    float cnew[8], obuf[8];
    unsigned short hhi[8], hlo[8];
    #pragma unroll
    for (int j = 0; j < 8; ++j) {
        const float cn = fv[j] * cold[j] + iv[j] * gv[j];
        const float hn = ov[j] * tanhf(cn);
        cnew[j] = cn;
        hhi[j] = f2bf(hn);
        hlo[j] = f2bf(hn - bf2f(hhi[j]));
        obuf[j] = hn * sc[j] + sh[j];
    }
    *(float4*)&cbuf[sb]     = *(float4*)&cnew[0];
    *(float4*)&cbuf[sb + 4] = *(float4*)&cnew[4];
    *(us4*)&ho_hi[sb]     = *(us4*)&hhi[0];
    *(us4*)&ho_hi[sb + 4] = *(us4*)&hhi[4];
    *(us4*)&ho_lo[sb]     = *(us4*)&hlo[0];
    *(us4*)&ho_lo[sb + 4] = *(us4*)&hlo[4];
    const size_t ob = ((size_t)((n * TT + t) * 4096 + y * 64 + xh * 32 + p)) * 64 + c8;
    *(float4*)&out[ob]     = *(float4*)&obuf[0];
    *(float4*)&out[ob + 4] = *(float4*)&obuf[4];
}

extern "C" void kernel_launch(void* const* d_in, const int* in_sizes, int n_in,
                              void* d_out, int out_size, void* d_ws, size_t ws_size,
                              hipStream_t stream) {
    const float* x     = (const float*)d_in[0];
    const float* Wx    = (const float*)d_in[1];
    const float* Wh    = (const float*)d_in[2];
    const float* b     = (const float*)d_in[3];
    const float* gamma = (const float*)d_in[4];
    const float* beta  = (const float*)d_in[5];
    const float* mean  = (const float*)d_in[6];
    const float* var   = (const float*)d_in[7];
    float* out = (float*)d_out;
    char* ws = (char*)d_ws;

    // ws layout (bytes):
    unsigned short* Wb    = (unsigned short*)(ws);            // 1,179,648
    float*          bn    = (float*)(ws + 1179648);           // 512
    unsigned short* hA_hi = (unsigned short*)(ws + 1180160);  // 1 MB
    unsigned short* hA_lo = (unsigned short*)(ws + 2228736);  // 1 MB
    float*          cbuf  = (float*)(ws + 3277312);           // 2 MB
    unsigned short* hB_hi = (unsigned short*)(ws + 5374464);  // 1 MB
    unsigned short* hB_lo = (unsigned short*)(ws + 6423040);  // 1 MB

    // zero hA (h0) + cbuf (c0) — contiguous 4 MB
    hipMemsetAsync(ws + 1180160, 0, 4194304, stream);
    prep_kernel<<<257, 256, 0, stream>>>(Wx, Wh, gamma, beta, mean, var, Wb, bn);

    for (int t = 0; t < TT; ++t) {
        const bool even = (t & 1) == 0;
        convstep_kernel<<<256, 256, 0, stream>>>(
            x,
            even ? hA_hi : hB_hi, even ? hA_lo : hB_lo,
            Wb, b, cbuf,
            even ? hB_hi : hA_hi, even ? hB_lo : hA_lo,
            bn, out, t);
    }
}

// Round 5
// 431.821 us; speedup vs baseline: 4.6779x; 2.1685x over previous
//
#include <hip/hip_runtime.h>
#include <cstddef>

typedef __attribute__((ext_vector_type(8))) short short8;
typedef __attribute__((ext_vector_type(4))) float f32x4;
typedef __attribute__((ext_vector_type(4))) unsigned short us4;

#define HW 64
#define TT 16
#define APAD 80                // shorts per (row,col) channel slot: 160 B, 16B-aligned
#define A_TILE (3*34*APAD)     // 8160 shorts per A tile
#define B_OFF  (4*A_TILE)      // 32640 shorts = 65280 B (16B-aligned)
#define CHUNK  8192            // shorts per 16KB weight chunk
#define NCHUNK 72

__device__ __forceinline__ unsigned short f2bf(float f) {
    unsigned u = __builtin_bit_cast(unsigned, f);
    u += 0x7fffu + ((u >> 16) & 1u);
    return (unsigned short)(u >> 16);
}
__device__ __forceinline__ float bf2f(unsigned short h) {
    unsigned u = ((unsigned)h) << 16;
    return __builtin_bit_cast(float, u);
}
__device__ __forceinline__ float hsig(float z) {
    return fminf(fmaxf(0.2f * z + 0.5f, 0.f), 1.f);
}

typedef __attribute__((address_space(3))) unsigned int lds_uint;
typedef const __attribute__((address_space(1))) unsigned int glb_uint;
__device__ __forceinline__ void async16(const void* g, void* l) {
    __builtin_amdgcn_global_load_lds((glb_uint*)g, (lds_uint*)l, 16, 0, 0);
}

#define WAITVM(N) { asm volatile("s_waitcnt vmcnt(" #N ")" ::: "memory"); \
                    __builtin_amdgcn_sched_barrier(0); }

// Weight pack: Wc flat short idx i = ((wslot*18+sub)*4 + kg)*2048 + n*8 + j
// value: (wslot<2 ? Wx : Wh)[(ky*3+kx)*64+c][n], hi for wslot even, lo for odd
// k5 = sub*32 + kg*8 + j; c=k5&63; q=k5>>6; kx=q%3; ky=q/3
__global__ __launch_bounds__(256) void prep_kernel(
    const float* __restrict__ Wx, const float* __restrict__ Wh,
    const float* __restrict__ gamma, const float* __restrict__ beta,
    const float* __restrict__ mean, const float* __restrict__ var,
    unsigned short* __restrict__ Wc, float* __restrict__ bn)
{
    if (blockIdx.x == 576) {
        if (threadIdx.x < 64) {
            const int c = threadIdx.x;
            const float inv = gamma[c] * rsqrtf(var[c] + 1e-3f);
            bn[c] = inv;
            bn[64 + c] = beta[c] - mean[c] * inv;
        }
        return;
    }
    const int gid = blockIdx.x * 256 + threadIdx.x;
    for (int i = gid; i < 589824; i += 576 * 256) {
        const int j  = i & 7;
        const int n  = (i >> 3) & 255;
        const int kg = (i >> 11) & 3;
        const int cs = i >> 13;            // 0..71
        const int sub = cs % 18, wslot = cs / 18;
        const int k5 = sub * 32 + kg * 8 + j;
        const int c = k5 & 63, q = k5 >> 6;
        const int kx = q % 3, ky = q / 3;
        const float* W = (wslot >= 2) ? Wh : Wx;
        const float v = W[(size_t)((ky * 3 + kx) * 64 + c) * 256 + n];
        const unsigned short hi = f2bf(v);
        Wc[i] = (wslot & 1) ? f2bf(v - bf2f(hi)) : hi;
    }
}

// One weight-pass with VERIFIED 16x16x32 fragments (round-2 layout).
// WSLOT in {0:Wx_hi, 1:Wx_lo, 2:Wh_hi, 3:Wh_lo}
template<int WSLOT, int NT>
__device__ __forceinline__ void conv_pass(
    const unsigned short* __restrict__ Wc,
    unsigned short* smem, const int tid,
    const unsigned short* abase,      // smem + p0*APAD + g*8
    const unsigned short* bbase,      // smem + B_OFF + (g*256 + w*64 + p0)*8
    f32x4 acc[2][4])
{
    constexpr int TILE0 = (WSLOT < 2) ? 0 : 2;
    #pragma unroll
    for (int sub = 0; sub < 18; ++sub) {
        const int ci = WSLOT * 18 + sub;
        // issue prefetch of chunk ci+3 (each wave stages exactly the rows it reads)
        if (ci + 3 < NCHUNK) {
            const int sc = ci + 3;
            const unsigned short* gsrc = Wc + (size_t)sc * CHUNK;
            unsigned short* ldst = smem + B_OFF + (sc & 3) * CHUNK;
            #pragma unroll
            for (int r = 0; r < 4; ++r)
                async16(gsrc + (r * 256 + tid) * 8, ldst + (r * 256 + tid) * 8);
        }
        // counted wait: chunk ci's 4 loads landed; keep 12 in flight mid-loop
        const int rem = 4 * (NCHUNK - 1 - ci);
        if (rem >= 12)      WAITVM(12)
        else if (rem == 8)  WAITVM(8)
        else if (rem == 4)  WAITVM(4)
        else                WAITVM(0)

        const int ky = sub / 6, kx = (sub / 2) % 3, cb = sub & 1;
        const int aimm = (ky * 34 + kx) * APAD + cb * 32;     // shorts
        const unsigned short* bbuf = bbase + (ci & 3) * CHUNK;

        // B frags: n = w*64 + nf*16 + p0, k-quarter = g (lane>>4), K=32 window
        short8 b[4];
        #pragma unroll
        for (int nf = 0; nf < 4; ++nf)
            b[nf] = *(const short8*)(bbuf + nf * 128);

        #pragma unroll
        for (int tt = 0; tt < NT; ++tt) {
            const unsigned short* at = abase + (TILE0 + tt) * A_TILE + aimm;
            const short8 a0 = *(const short8*)(at);               // rows 0..15
            const short8 a1 = *(const short8*)(at + 16 * APAD);   // rows 16..31
            #pragma unroll
            for (int nf = 0; nf < 4; ++nf) {
                acc[0][nf] = __builtin_amdgcn_mfma_f32_16x16x32_bf16(a0, b[nf], acc[0][nf], 0, 0, 0);
                acc[1][nf] = __builtin_amdgcn_mfma_f32_16x16x32_bf16(a1, b[nf], acc[1][nf], 0, 0, 0);
            }
        }
    }
}

// Per-timestep fused conv + gates + state + BN. Block = (n,y,xhalf): 32 px x 256 ch.
__global__ __launch_bounds__(256) void convstep_kernel(
    const float* __restrict__ x,
    const unsigned short* __restrict__ hb_hi,
    const unsigned short* __restrict__ hb_lo,
    const unsigned short* __restrict__ Wc,
    const float* __restrict__ bias,
    float* __restrict__ cbuf,
    unsigned short* __restrict__ ho_hi,
    unsigned short* __restrict__ ho_lo,
    const float* __restrict__ bn,
    float* __restrict__ out,
    const int t)
{
    const int bid = blockIdx.x;
    const int xh = bid & 1;
    const int y  = (bid >> 1) & 63;
    const int n  = bid >> 7;
    const int tid = threadIdx.x;
    const int lane = tid & 63;
    const int w = tid >> 6;

    // A: 4 tiles [3][34][80] bf16 = 65280 B ; B: 4 chunk buffers = 65536 B
    __shared__ __align__(16) unsigned short smem[4 * A_TILE + 4 * CHUNK];

    // ---- stage A tiles (x_hi, x_lo, h_hi, h_lo) ----
    const float* __restrict__ xt = x + (size_t)(n * TT + t) * 4096 * 64;
    const size_t hbase = (size_t)n * 4096 * 64;
    for (int idx = tid; idx < 2 * 3 * 34 * 16; idx += 256) {
        const int cg  = idx & 15;
        const int col = (idx >> 4) % 34;
        const int i3  = (idx >> 4) / 34;
        const int r   = i3 % 3;
        const int src = i3 / 3;             // 0=x, 1=h
        const int gy = y + r - 1;
        const int gx = xh * 32 + col - 1;
        const bool ok = ((unsigned)gy < 64u) && ((unsigned)gx < 64u);
        const int ebase = (r * 34 + col) * APAD + cg * 4;
        if (src == 0) {
            float4 v = make_float4(0.f, 0.f, 0.f, 0.f);
            if (ok) v = *(const float4*)(xt + (size_t)(gy * 64 + gx) * 64 + cg * 4);
            us4 hi, lo;
            hi.x = f2bf(v.x); lo.x = f2bf(v.x - bf2f(hi.x));
            hi.y = f2bf(v.y); lo.y = f2bf(v.y - bf2f(hi.y));
            hi.z = f2bf(v.z); lo.z = f2bf(v.z - bf2f(hi.z));
            hi.w = f2bf(v.w); lo.w = f2bf(v.w - bf2f(hi.w));
            *(us4*)&smem[0 * A_TILE + ebase] = hi;
            *(us4*)&smem[1 * A_TILE + ebase] = lo;
        } else {
            us4 hi = {0, 0, 0, 0}, lo = {0, 0, 0, 0};
            if (ok) {
                const size_t off = hbase + (size_t)(gy * 64 + gx) * 64 + cg * 4;
                hi = *(const us4*)(hb_hi + off);
                lo = *(const us4*)(hb_lo + off);
            }
            *(us4*)&smem[2 * A_TILE + ebase] = hi;
            *(us4*)&smem[3 * A_TILE + ebase] = lo;
        }
    }

    // ---- prologue: stage weight chunks 0..2 ----
    #pragma unroll
    for (int sc = 0; sc < 3; ++sc) {
        const unsigned short* gsrc = Wc + (size_t)sc * CHUNK;
        unsigned short* ldst = smem + B_OFF + sc * CHUNK;
        #pragma unroll
        for (int r = 0; r < 4; ++r)
            async16(gsrc + (r * 256 + tid) * 8, ldst + (r * 256 + tid) * 8);
    }
    __syncthreads();   // drains vmcnt(0): A tiles + chunks 0..2 all valid

    // ---- K-loop: 72 chunks, no barriers (each wave stages its own B rows) ----
    const int p0 = lane & 15;
    const int g  = lane >> 4;
    const unsigned short* abase = smem + p0 * APAD + g * 8;
    const unsigned short* bbase = smem + B_OFF + ((g * 256) + w * 64 + p0) * 8;

    f32x4 acc[2][4] = {};
    conv_pass<0, 2>(Wc, smem, tid, abase, bbase, acc);
    conv_pass<1, 1>(Wc, smem, tid, abase, bbase, acc);
    conv_pass<2, 2>(Wc, smem, tid, abase, bbase, acc);
    conv_pass<3, 1>(Wc, smem, tid, abase, bbase, acc);

    // ---- gates -> LDS gate buffer (overlay A region), round-2 verified mapping ----
    __syncthreads();
    float* gbuf = (float*)smem;            // [4 gates][32 px][68] f32 = 34816 B

    float bv[4];
    #pragma unroll
    for (int nf = 0; nf < 4; ++nf) bv[nf] = bias[w * 64 + nf * 16 + p0];

    #pragma unroll
    for (int mf = 0; mf < 2; ++mf)
        #pragma unroll
        for (int nf = 0; nf < 4; ++nf)
            #pragma unroll
            for (int j = 0; j < 4; ++j) {
                float v = acc[mf][nf][j] + bv[nf];
                v = (w == 2) ? tanhf(v) : hsig(v);   // gate order i,f,g,o
                const int px = mf * 16 + g * 4 + j;
                gbuf[(w * 32 + px) * 68 + nf * 16 + p0] = v;
            }
    __syncthreads();

    // ---- state update + BN output: thread -> (pixel, 8 channels) ----
    const int p  = tid >> 3;
    const int c8 = (tid & 7) * 8;
    const float* g0 = &gbuf[(0 * 32 + p) * 68 + c8];
    const float* g1 = &gbuf[(1 * 32 + p) * 68 + c8];
    const float* g2 = &gbuf[(2 * 32 + p) * 68 + c8];
    const float* g3 = &gbuf[(3 * 32 + p) * 68 + c8];
    const size_t gpix = (size_t)((n * 64 + y) * 64 + xh * 32 + p);
    const size_t sb = gpix * 64 + c8;

    float iv[8], fv[8], gv[8], ov[8], cold[8], sc[8], sh[8];
    *(float4*)&iv[0] = *(const float4*)g0;       *(float4*)&iv[4] = *(const float4*)(g0 + 4);
    *(float4*)&fv[0] = *(const float4*)g1;       *(float4*)&fv[4] = *(const float4*)(g1 + 4);
    *(float4*)&gv[0] = *(const float4*)g2;       *(float4*)&gv[4] = *(const float4*)(g2 + 4);
    *(float4*)&ov[0] = *(const float4*)g3;       *(float4*)&ov[4] = *(const float4*)(g3 + 4);
    *(float4*)&cold[0] = *(const float4*)&cbuf[sb];      *(float4*)&cold[4] = *(const float4*)&cbuf[sb + 4];
    *(float4*)&sc[0] = *(const float4*)&bn[c8];          *(float4*)&sc[4] = *(const float4*)&bn[c8 + 4];
    *(float4*)&sh[0] = *(const float4*)&bn[64 + c8];     *(float4*)&sh[4] = *(const float4*)&bn[64 + c8 + 4];

    float cnew[8], obuf[8];
    unsigned short hhi[8], hlo[8];
    #pragma unroll
    for (int j = 0; j < 8; ++j) {
        const float cn = fv[j] * cold[j] + iv[j] * gv[j];
        const float hn = ov[j] * tanhf(cn);
        cnew[j] = cn;
        hhi[j] = f2bf(hn);
        hlo[j] = f2bf(hn - bf2f(hhi[j]));
        obuf[j] = hn * sc[j] + sh[j];
    }
    *(float4*)&cbuf[sb]     = *(float4*)&cnew[0];
    *(float4*)&cbuf[sb + 4] = *(float4*)&cnew[4];
    *(us4*)&ho_hi[sb]     = *(us4*)&hhi[0];
    *(us4*)&ho_hi[sb + 4] = *(us4*)&hhi[4];
    *(us4*)&ho_lo[sb]     = *(us4*)&hlo[0];
    *(us4*)&ho_lo[sb + 4] = *(us4*)&hlo[4];
    const size_t ob = ((size_t)((n * TT + t) * 4096 + y * 64 + xh * 32 + p)) * 64 + c8;
    *(float4*)&out[ob]     = *(float4*)&obuf[0];
    *(float4*)&out[ob + 4] = *(float4*)&obuf[4];
}

extern "C" void kernel_launch(void* const* d_in, const int* in_sizes, int n_in,
                              void* d_out, int out_size, void* d_ws, size_t ws_size,
                              hipStream_t stream) {
    const float* x     = (const float*)d_in[0];
    const float* Wx    = (const float*)d_in[1];
    const float* Wh    = (const float*)d_in[2];
    const float* b     = (const float*)d_in[3];
    const float* gamma = (const float*)d_in[4];
    const float* beta  = (const float*)d_in[5];
    const float* mean  = (const float*)d_in[6];
    const float* var   = (const float*)d_in[7];
    float* out = (float*)d_out;
    char* ws = (char*)d_ws;

    unsigned short* Wc    = (unsigned short*)(ws);            // 1,179,648 B
    float*          bn    = (float*)(ws + 1179648);           // 512 B
    unsigned short* hA_hi = (unsigned short*)(ws + 1180160);  // 1 MB
    unsigned short* hA_lo = (unsigned short*)(ws + 2228736);  // 1 MB
    float*          cbuf  = (float*)(ws + 3277312);           // 2 MB
    unsigned short* hB_hi = (unsigned short*)(ws + 5374464);  // 1 MB
    unsigned short* hB_lo = (unsigned short*)(ws + 6423040);  // 1 MB

    hipMemsetAsync(ws + 1180160, 0, 4194304, stream);         // h0 + c0 = 0
    prep_kernel<<<577, 256, 0, stream>>>(Wx, Wh, gamma, beta, mean, var, Wc, bn);

    for (int t = 0; t < TT; ++t) {
        const bool even = (t & 1) == 0;
        convstep_kernel<<<256, 256, 0, stream>>>(
            x,
            even ? hA_hi : hB_hi, even ? hA_lo : hB_lo,
            Wc, b, cbuf,
            even ? hB_hi : hA_hi, even ? hB_lo : hA_lo,
            bn, out, t);
    }
}

// Round 6
// 385.721 us; speedup vs baseline: 5.2369x; 1.1195x over previous
//
#include <hip/hip_runtime.h>
#include <cstddef>

typedef __attribute__((ext_vector_type(8))) short short8;
typedef __attribute__((ext_vector_type(4))) float f32x4;
typedef __attribute__((ext_vector_type(4))) unsigned short us4;

#define HW 64
#define TT 16
#define APAD 72                // shorts per (row,col) slot: 144 B = 9x16B, aligned
#define A_TILE (3*34*APAD)     // 7344 shorts per A tile
#define B_OFF  (4*A_TILE)      // 29376 shorts = 58752 B (16B-aligned)
#define CHUNK  8192            // shorts per 16KB weight chunk
#define NCHUNK 72

__device__ __forceinline__ unsigned short f2bf(float f) {
    unsigned u = __builtin_bit_cast(unsigned, f);
    u += 0x7fffu + ((u >> 16) & 1u);
    return (unsigned short)(u >> 16);
}
__device__ __forceinline__ float bf2f(unsigned short h) {
    unsigned u = ((unsigned)h) << 16;
    return __builtin_bit_cast(float, u);
}
__device__ __forceinline__ float hsig(float z) {
    return fminf(fmaxf(0.2f * z + 0.5f, 0.f), 1.f);
}

typedef __attribute__((address_space(3))) unsigned int lds_uint;
typedef const __attribute__((address_space(1))) unsigned int glb_uint;
__device__ __forceinline__ void async16(const void* g, void* l) {
    __builtin_amdgcn_global_load_lds((glb_uint*)g, (lds_uint*)l, 16, 0, 0);
}

#define WAITVM(N) { asm volatile("s_waitcnt vmcnt(" #N ")" ::: "memory"); \
                    __builtin_amdgcn_sched_barrier(0); }

// Weight pack (unchanged from round 5): Wc short idx i = ((wslot*18+sub)*4 + kg)*2048 + n*8 + j
// value: (wslot<2 ? Wx : Wh)[(ky*3+kx)*64+c][n], hi for wslot even, lo for odd
// k5 = sub*32 + kg*8 + j; c=k5&63; q=k5>>6; kx=q%3; ky=q/3
__global__ __launch_bounds__(256) void prep_kernel(
    const float* __restrict__ Wx, const float* __restrict__ Wh,
    const float* __restrict__ gamma, const float* __restrict__ beta,
    const float* __restrict__ mean, const float* __restrict__ var,
    unsigned short* __restrict__ Wc, float* __restrict__ bn)
{
    if (blockIdx.x == 576) {
        if (threadIdx.x < 64) {
            const int c = threadIdx.x;
            const float inv = gamma[c] * rsqrtf(var[c] + 1e-3f);
            bn[c] = inv;
            bn[64 + c] = beta[c] - mean[c] * inv;
        }
        return;
    }
    const int gid = blockIdx.x * 256 + threadIdx.x;
    for (int i = gid; i < 589824; i += 576 * 256) {
        const int j  = i & 7;
        const int n  = (i >> 3) & 255;
        const int kg = (i >> 11) & 3;
        const int cs = i >> 13;            // 0..71
        const int sub = cs % 18, wslot = cs / 18;
        const int k5 = sub * 32 + kg * 8 + j;
        const int c = k5 & 63, q = k5 >> 6;
        const int kx = q % 3, ky = q / 3;
        const float* W = (wslot >= 2) ? Wh : Wx;
        const float v = W[(size_t)((ky * 3 + kx) * 64 + c) * 256 + n];
        const unsigned short hi = f2bf(v);
        Wc[i] = (wslot & 1) ? f2bf(v - bf2f(hi)) : hi;
    }
}

// One weight-pass, 8-wave version. WSLOT in {0:Wx_hi, 1:Wx_lo, 2:Wh_hi, 3:Wh_lo}
// Each wave stages its own 2KB chunk slice (wave-major LDS layout) and reads it back.
template<int WSLOT, int NT>
__device__ __forceinline__ void conv_pass(
    const unsigned short* __restrict__ Wc,
    const int soff0, const int soff1,            // per-lane global short-offsets in chunk
    unsigned short* lds0, unsigned short* lds1,  // per-lane LDS dst (buffer 0)
    const unsigned short* abase,
    const unsigned short* bbase,
    f32x4 acc[2][2])
{
    constexpr int TILE0 = (WSLOT < 2) ? 0 : 2;
    #pragma unroll
    for (int sub = 0; sub < 18; ++sub) {
        const int ci = WSLOT * 18 + sub;
        // prefetch chunk ci+3 (this wave's 2KB slice only)
        if (ci + 3 < NCHUNK) {
            const int sc = ci + 3;
            const unsigned short* gsc = Wc + (size_t)sc * CHUNK;
            const int bsel = (sc & 3) * CHUNK;
            async16(gsc + soff0, lds0 + bsel);
            async16(gsc + soff1, lds1 + bsel);
        }
        // counted wait: chunk ci's 2 loads landed; keep 6 in flight mid-loop
        const int rem = NCHUNK - 1 - ci;
        if (rem >= 3)      WAITVM(6)
        else if (rem == 2) WAITVM(4)
        else if (rem == 1) WAITVM(2)
        else               WAITVM(0)

        const int ky = sub / 6, kx = (sub / 2) % 3, cb = sub & 1;
        const int aimm = (ky * 34 + kx) * APAD + cb * 32;     // shorts
        const unsigned short* bbuf = bbase + (ci & 3) * CHUNK;

        short8 b[2];
        b[0] = *(const short8*)(bbuf);
        b[1] = *(const short8*)(bbuf + 128);

        #pragma unroll
        for (int tt = 0; tt < NT; ++tt) {
            const unsigned short* at = abase + (TILE0 + tt) * A_TILE + aimm;
            const short8 a0 = *(const short8*)(at);               // rows 0..15
            const short8 a1 = *(const short8*)(at + 16 * APAD);   // rows 16..31
            #pragma unroll
            for (int nf = 0; nf < 2; ++nf) {
                acc[0][nf] = __builtin_amdgcn_mfma_f32_16x16x32_bf16(a0, b[nf], acc[0][nf], 0, 0, 0);
                acc[1][nf] = __builtin_amdgcn_mfma_f32_16x16x32_bf16(a1, b[nf], acc[1][nf], 0, 0, 0);
            }
        }
    }
}

// Per-timestep fused conv + gates + state + BN. Block = (n,y,xhalf): 32 px x 256 ch.
// 512 threads = 8 waves (2/SIMD); wave w owns channels n in [w*32, w*32+32).
__global__ __launch_bounds__(512) void convstep_kernel(
    const float* __restrict__ x,
    const unsigned short* __restrict__ hb_hi,
    const unsigned short* __restrict__ hb_lo,
    const unsigned short* __restrict__ Wc,
    const float* __restrict__ bias,
    float* __restrict__ cbuf,
    unsigned short* __restrict__ ho_hi,
    unsigned short* __restrict__ ho_lo,
    const float* __restrict__ bn,
    float* __restrict__ out,
    const int t)
{
    const int bid = blockIdx.x;
    const int xh = bid & 1;
    const int y  = (bid >> 1) & 63;
    const int n  = bid >> 7;
    const int tid = threadIdx.x;
    const int lane = tid & 63;
    const int w = tid >> 6;              // wave 0..7

    // A: 4 tiles [3][34][72] bf16 = 58752 B ; B: 4 chunk buffers = 65536 B -> 124288 B
    __shared__ __align__(16) unsigned short smem[4 * A_TILE + 4 * CHUNK];

    // ---- stage A tiles (x_hi, x_lo, h_hi, h_lo) ----
    const float* __restrict__ xt = x + (size_t)(n * TT + t) * 4096 * 64;
    const size_t hbase = (size_t)n * 4096 * 64;
    for (int idx = tid; idx < 2 * 3 * 34 * 16; idx += 512) {
        const int cg  = idx & 15;
        const int col = (idx >> 4) % 34;
        const int i3  = (idx >> 4) / 34;
        const int r   = i3 % 3;
        const int src = i3 / 3;             // 0=x, 1=h
        const int gy = y + r - 1;
        const int gx = xh * 32 + col - 1;
        const bool ok = ((unsigned)gy < 64u) && ((unsigned)gx < 64u);
        const int ebase = (r * 34 + col) * APAD + cg * 4;
        if (src == 0) {
            float4 v = make_float4(0.f, 0.f, 0.f, 0.f);
            if (ok) v = *(const float4*)(xt + (size_t)(gy * 64 + gx) * 64 + cg * 4);
            us4 hi, lo;
            hi.x = f2bf(v.x); lo.x = f2bf(v.x - bf2f(hi.x));
            hi.y = f2bf(v.y); lo.y = f2bf(v.y - bf2f(hi.y));
            hi.z = f2bf(v.z); lo.z = f2bf(v.z - bf2f(hi.z));
            hi.w = f2bf(v.w); lo.w = f2bf(v.w - bf2f(hi.w));
            *(us4*)&smem[0 * A_TILE + ebase] = hi;
            *(us4*)&smem[1 * A_TILE + ebase] = lo;
        } else {
            us4 hi = {0, 0, 0, 0}, lo = {0, 0, 0, 0};
            if (ok) {
                const size_t off = hbase + (size_t)(gy * 64 + gx) * 64 + cg * 4;
                hi = *(const us4*)(hb_hi + off);
                lo = *(const us4*)(hb_lo + off);
            }
            *(us4*)&smem[2 * A_TILE + ebase] = hi;
            *(us4*)&smem[3 * A_TILE + ebase] = lo;
        }
    }

    // per-lane staging addresses: wave w stages rows n=w*32..w*32+31, all 4 kg
    // load r covers elems idx=r*64+lane: kg=idx>>5, row=idx&31
    const int soff0 = ((lane >> 5)    ) * 2048 + (w * 32 + (lane & 31)) * 8;
    const int soff1 = ((lane >> 5) + 2) * 2048 + (w * 32 + (lane & 31)) * 8;
    unsigned short* lds0 = smem + B_OFF + w * 1024 + (lane      ) * 8;
    unsigned short* lds1 = smem + B_OFF + w * 1024 + (64 + lane ) * 8;

    // ---- prologue: stage weight chunks 0..2 ----
    #pragma unroll
    for (int sc = 0; sc < 3; ++sc) {
        const unsigned short* gsc = Wc + (size_t)sc * CHUNK;
        async16(gsc + soff0, lds0 + sc * CHUNK);
        async16(gsc + soff1, lds1 + sc * CHUNK);
    }
    __syncthreads();   // drains vmcnt(0): A tiles + chunks 0..2 valid

    // ---- K-loop: 72 chunks, no barriers ----
    const int p0 = lane & 15;
    const int g  = lane >> 4;
    const unsigned short* abase = smem + p0 * APAD + g * 8;
    const unsigned short* bbase = smem + B_OFF + w * 1024 + (g * 32 + p0) * 8;

    f32x4 acc[2][2] = {};
    conv_pass<0, 2>(Wc, soff0, soff1, lds0, lds1, abase, bbase, acc);
    conv_pass<1, 1>(Wc, soff0, soff1, lds0, lds1, abase, bbase, acc);
    conv_pass<2, 2>(Wc, soff0, soff1, lds0, lds1, abase, bbase, acc);
    conv_pass<3, 1>(Wc, soff0, soff1, lds0, lds1, abase, bbase, acc);

    // ---- gates -> LDS gate buffer (overlay A region) ----
    __syncthreads();
    float* gbuf = (float*)smem;            // [4 gates][32 px][68] f32 = 34816 B
    const int gate = w >> 1;
    const int chalf = (w & 1) * 32;

    float bv[2];
    bv[0] = bias[w * 32 + p0];
    bv[1] = bias[w * 32 + 16 + p0];

    #pragma unroll
    for (int mf = 0; mf < 2; ++mf)
        #pragma unroll
        for (int nf = 0; nf < 2; ++nf)
            #pragma unroll
            for (int j = 0; j < 4; ++j) {
                float v = acc[mf][nf][j] + bv[nf];
                v = (gate == 2) ? tanhf(v) : hsig(v);   // gate order i,f,g,o
                const int px = mf * 16 + g * 4 + j;
                gbuf[(gate * 32 + px) * 68 + chalf + nf * 16 + p0] = v;
            }
    __syncthreads();

    // ---- state update + BN output: thread -> (pixel, 4 channels) ----
    const int p  = tid >> 4;
    const int c4 = (tid & 15) * 4;
    const float4 iv = *(const float4*)&gbuf[(0 * 32 + p) * 68 + c4];
    const float4 fv = *(const float4*)&gbuf[(1 * 32 + p) * 68 + c4];
    const float4 gv = *(const float4*)&gbuf[(2 * 32 + p) * 68 + c4];
    const float4 ov = *(const float4*)&gbuf[(3 * 32 + p) * 68 + c4];
    const size_t gpix = (size_t)((n * 64 + y) * 64 + xh * 32 + p);
    const size_t sb = gpix * 64 + c4;
    const float4 cold = *(const float4*)&cbuf[sb];
    const float4 scv  = *(const float4*)&bn[c4];
    const float4 shv  = *(const float4*)&bn[64 + c4];

    float ivv[4] = {iv.x, iv.y, iv.z, iv.w};
    float fvv[4] = {fv.x, fv.y, fv.z, fv.w};
    float gvv[4] = {gv.x, gv.y, gv.z, gv.w};
    float ovv[4] = {ov.x, ov.y, ov.z, ov.w};
    float cov[4] = {cold.x, cold.y, cold.z, cold.w};
    float scc[4] = {scv.x, scv.y, scv.z, scv.w};
    float shh[4] = {shv.x, shv.y, shv.z, shv.w};

    float cnew[4], obuf[4];
    us4 hhi, hlo;
    unsigned short* hhp = (unsigned short*)&hhi;
    unsigned short* hlp = (unsigned short*)&hlo;
    #pragma unroll
    for (int j = 0; j < 4; ++j) {
        const float cn = fvv[j] * cov[j] + ivv[j] * gvv[j];
        const float hn = ovv[j] * tanhf(cn);
        cnew[j] = cn;
        hhp[j] = f2bf(hn);
        hlp[j] = f2bf(hn - bf2f(hhp[j]));
        obuf[j] = hn * scc[j] + shh[j];
    }
    *(float4*)&cbuf[sb] = *(float4*)&cnew[0];
    *(us4*)&ho_hi[sb]   = hhi;
    *(us4*)&ho_lo[sb]   = hlo;
    const size_t ob = ((size_t)((n * TT + t) * 4096 + y * 64 + xh * 32 + p)) * 64 + c4;
    *(float4*)&out[ob] = *(float4*)&obuf[0];
}

extern "C" void kernel_launch(void* const* d_in, const int* in_sizes, int n_in,
                              void* d_out, int out_size, void* d_ws, size_t ws_size,
                              hipStream_t stream) {
    const float* x     = (const float*)d_in[0];
    const float* Wx    = (const float*)d_in[1];
    const float* Wh    = (const float*)d_in[2];
    const float* b     = (const float*)d_in[3];
    const float* gamma = (const float*)d_in[4];
    const float* beta  = (const float*)d_in[5];
    const float* mean  = (const float*)d_in[6];
    const float* var   = (const float*)d_in[7];
    float* out = (float*)d_out;
    char* ws = (char*)d_ws;

    unsigned short* Wc    = (unsigned short*)(ws);            // 1,179,648 B
    float*          bn    = (float*)(ws + 1179648);           // 512 B
    unsigned short* hA_hi = (unsigned short*)(ws + 1180160);  // 1 MB
    unsigned short* hA_lo = (unsigned short*)(ws + 2228736);  // 1 MB
    float*          cbuf  = (float*)(ws + 3277312);           // 2 MB
    unsigned short* hB_hi = (unsigned short*)(ws + 5374464);  // 1 MB
    unsigned short* hB_lo = (unsigned short*)(ws + 6423040);  // 1 MB

    hipMemsetAsync(ws + 1180160, 0, 4194304, stream);         // h0 + c0 = 0
    prep_kernel<<<577, 256, 0, stream>>>(Wx, Wh, gamma, beta, mean, var, Wc, bn);

    for (int t = 0; t < TT; ++t) {
        const bool even = (t & 1) == 0;
        convstep_kernel<<<256, 512, 0, stream>>>(
            x,
            even ? hA_hi : hB_hi, even ? hA_lo : hB_lo,
            Wc, b, cbuf,
            even ? hB_hi : hA_hi, even ? hB_lo : hA_lo,
            bn, out, t);
    }
}

// Round 8
// 216.576 us; speedup vs baseline: 9.3270x; 1.7810x over previous
//
#include <hip/hip_runtime.h>
#include <cstddef>

typedef __attribute__((ext_vector_type(8))) _Float16 half8;
typedef __attribute__((ext_vector_type(4))) float f32x4;
typedef __attribute__((ext_vector_type(4))) unsigned short us4;

#define TT 16
#define APAD 72                // shorts per (row,col) slot: 144 B
#define A_TILE (3*34*APAD)     // 7344 shorts per A tile (x, h)
#define B_OFF  (2*A_TILE)      // 14688 shorts = 29376 B
#define CHUNK  8192            // shorts per 16KB weight chunk
#define NCHUNK 36
#define NBUF   6               // LDS chunk buffers
#define PFDIST 5               // prefetch distance; MUST be < NBUF (buffer-reuse race)

__device__ __forceinline__ unsigned short f2h(float f) {
    return __builtin_bit_cast(unsigned short, (_Float16)f);
}
__device__ __forceinline__ float hsig(float z) {
    return fminf(fmaxf(0.2f * z + 0.5f, 0.f), 1.f);
}

typedef __attribute__((address_space(3))) unsigned int lds_uint;
typedef const __attribute__((address_space(1))) unsigned int glb_uint;
__device__ __forceinline__ void async16(const void* g, void* l) {
    __builtin_amdgcn_global_load_lds((glb_uint*)g, (lds_uint*)l, 16, 0, 0);
}

#define WAITVM(N) { asm volatile("s_waitcnt vmcnt(" #N ")" ::: "memory"); \
                    __builtin_amdgcn_sched_barrier(0); }

// Weight pack (fp16): Wc short idx i = (s*4 + kg)*2048 + n*8 + j, s in [0,36)
// s<18 -> Wx chunk sub=s ; s>=18 -> Wh chunk sub=s-18
// k5 = sub*32 + kg*8 + j; c=k5&63; q=k5>>6; kx=q%3; ky=q/3
__global__ __launch_bounds__(256) void prep_kernel(
    const float* __restrict__ Wx, const float* __restrict__ Wh,
    const float* __restrict__ gamma, const float* __restrict__ beta,
    const float* __restrict__ mean, const float* __restrict__ var,
    unsigned short* __restrict__ Wc, float* __restrict__ bn)
{
    if (blockIdx.x == 1152) {
        if (threadIdx.x < 64) {
            const int c = threadIdx.x;
            const float inv = gamma[c] * rsqrtf(var[c] + 1e-3f);
            bn[c] = inv;
            bn[64 + c] = beta[c] - mean[c] * inv;
        }
        return;
    }
    const int i = blockIdx.x * 256 + threadIdx.x;   // < 294912
    const int j  = i & 7;
    const int n  = (i >> 3) & 255;
    const int kg = (i >> 11) & 3;
    const int s  = i >> 13;            // 0..35
    const int sub = s % 18;
    const float* W = (s >= 18) ? Wh : Wx;
    const int k5 = sub * 32 + kg * 8 + j;
    const int c = k5 & 63, q = k5 >> 6;
    const int kx = q % 3, ky = q / 3;
    Wc[i] = f2h(W[(size_t)((ky * 3 + kx) * 64 + c) * 256 + n]);
}

// One conv pass: PASS 0 = x * Wx (chunks 0..17), PASS 1 = h * Wh (chunks 18..35)
template<int PASS>
__device__ __forceinline__ void conv_pass(
    const unsigned short* __restrict__ Wc,
    const int soff0, const int soff1,
    unsigned short* lds0, unsigned short* lds1,
    const unsigned short* abase,
    const unsigned short* bbase,
    f32x4 acc[2][2])
{
    #pragma unroll
    for (int sub = 0; sub < 18; ++sub) {
        const int ci = PASS * 18 + sub;
        // prefetch chunk ci+PFDIST into buffer (ci+PFDIST)%NBUF != ci%NBUF (no reuse race)
        if (ci + PFDIST < NCHUNK) {
            const int sc = ci + PFDIST;
            const unsigned short* gsc = Wc + (size_t)sc * CHUNK;
            const int bsel = (sc % NBUF) * CHUNK;
            async16(gsc + soff0, lds0 + bsel);
            async16(gsc + soff1, lds1 + bsel);
        }
        // counted wait: chunk ci's 2 loads landed; keep up to 10 in flight
        const int rem = NCHUNK - 1 - ci;
        if (rem >= PFDIST) WAITVM(10)
        else if (rem == 4) WAITVM(8)
        else if (rem == 3) WAITVM(6)
        else if (rem == 2) WAITVM(4)
        else if (rem == 1) WAITVM(2)
        else               WAITVM(0)

        const int ky = sub / 6, kx = (sub / 2) % 3, cb = sub & 1;
        const int aimm = (ky * 34 + kx) * APAD + cb * 32;     // shorts
        const unsigned short* bbuf = bbase + (ci % NBUF) * CHUNK;

        const half8 b0 = *(const half8*)(bbuf);
        const half8 b1 = *(const half8*)(bbuf + 128);
        const unsigned short* at = abase + PASS * A_TILE + aimm;
        const half8 a0 = *(const half8*)(at);                 // pixels 0..15
        const half8 a1 = *(const half8*)(at + 16 * APAD);     // pixels 16..31
        acc[0][0] = __builtin_amdgcn_mfma_f32_16x16x32_f16(a0, b0, acc[0][0], 0, 0, 0);
        acc[0][1] = __builtin_amdgcn_mfma_f32_16x16x32_f16(a0, b1, acc[0][1], 0, 0, 0);
        acc[1][0] = __builtin_amdgcn_mfma_f32_16x16x32_f16(a1, b0, acc[1][0], 0, 0, 0);
        acc[1][1] = __builtin_amdgcn_mfma_f32_16x16x32_f16(a1, b1, acc[1][1], 0, 0, 0);
    }
}

// Per-timestep fused conv + gates + state + BN. Block = (n,y,xhalf): 32 px x 256 ch.
// 512 threads = 8 waves; wave w owns channels [w*32, w*32+32).
__global__ __launch_bounds__(512) void convstep_kernel(
    const float* __restrict__ x,
    const unsigned short* __restrict__ hb,   // (B,4096,64) fp16 state in
    const unsigned short* __restrict__ Wc,
    const float* __restrict__ bias,
    float* __restrict__ cbuf,
    unsigned short* __restrict__ ho,         // fp16 state out (ping-pong)
    const float* __restrict__ bn,
    float* __restrict__ out,
    const int t)
{
    const int bid0 = blockIdx.x;
    const int bid = (bid0 & 7) * 32 + (bid0 >> 3);   // bijective XCD swizzle (256 = 8*32)
    const int xh = bid & 1;
    const int y  = (bid >> 1) & 63;
    const int n  = bid >> 7;
    const int tid = threadIdx.x;
    const int lane = tid & 63;
    const int w = tid >> 6;              // wave 0..7

    // A: 2 tiles [3][34][72] fp16 = 29376 B ; B: 6 chunk buffers = 98304 B -> 127680 B
    __shared__ __align__(16) unsigned short smem[B_OFF + NBUF * CHUNK];

    // ---- stage A tiles (x fp16, h fp16) ----
    const float* __restrict__ xt = x + (size_t)(n * TT + t) * 4096 * 64;
    const size_t hbase = (size_t)n * 4096 * 64;
    for (int idx = tid; idx < 2 * 3 * 34 * 8; idx += 512) {
        const int cg  = idx & 7;            // 8-channel group
        const int col = (idx >> 3) % 34;
        const int i3  = (idx >> 3) / 34;
        const int r   = i3 % 3;
        const int src = i3 / 3;             // 0=x, 1=h
        const int gy = y + r - 1;
        const int gx = xh * 32 + col - 1;
        const bool ok = ((unsigned)gy < 64u) && ((unsigned)gx < 64u);
        const int ebase = (r * 34 + col) * APAD + cg * 8;
        if (src == 0) {
            float4 v0 = make_float4(0.f, 0.f, 0.f, 0.f), v1 = v0;
            if (ok) {
                const float* p = xt + (size_t)(gy * 64 + gx) * 64 + cg * 8;
                v0 = *(const float4*)p;
                v1 = *(const float4*)(p + 4);
            }
            us4 h0, h1;
            h0.x = f2h(v0.x); h0.y = f2h(v0.y); h0.z = f2h(v0.z); h0.w = f2h(v0.w);
            h1.x = f2h(v1.x); h1.y = f2h(v1.y); h1.z = f2h(v1.z); h1.w = f2h(v1.w);
            *(us4*)&smem[ebase]     = h0;
            *(us4*)&smem[ebase + 4] = h1;
        } else {
            uint4 v = make_uint4(0u, 0u, 0u, 0u);
            if (ok) v = *(const uint4*)(hb + hbase + (size_t)(gy * 64 + gx) * 64 + cg * 8);
            *(uint4*)&smem[A_TILE + ebase] = v;
        }
    }

    // per-lane staging addresses: wave w stages rows n=w*32..w*32+31, all 4 kg
    const int soff0 = ((lane >> 5)    ) * 2048 + (w * 32 + (lane & 31)) * 8;
    const int soff1 = ((lane >> 5) + 2) * 2048 + (w * 32 + (lane & 31)) * 8;
    unsigned short* lds0 = smem + B_OFF + w * 1024 + (lane     ) * 8;
    unsigned short* lds1 = smem + B_OFF + w * 1024 + (64 + lane) * 8;

    // ---- prologue: stage weight chunks 0..PFDIST-1 ----
    #pragma unroll
    for (int sc = 0; sc < PFDIST; ++sc) {
        const unsigned short* gsc = Wc + (size_t)sc * CHUNK;
        async16(gsc + soff0, lds0 + sc * CHUNK);
        async16(gsc + soff1, lds1 + sc * CHUNK);
    }
    __syncthreads();   // barrier drains vmcnt(0): A tiles + chunks 0..4 valid

    // ---- K-loop: 36 chunks, no barriers (each wave stages its own B rows) ----
    const int p0 = lane & 15;
    const int g  = lane >> 4;
    const unsigned short* abase = smem + p0 * APAD + g * 8;
    const unsigned short* bbase = smem + B_OFF + w * 1024 + (g * 32 + p0) * 8;

    f32x4 acc[2][2] = {};
    conv_pass<0>(Wc, soff0, soff1, lds0, lds1, abase, bbase, acc);
    conv_pass<1>(Wc, soff0, soff1, lds0, lds1, abase, bbase, acc);

    // ---- gates -> LDS gate buffer (overlay; all chunk reads done) ----
    __syncthreads();
    float* gbuf = (float*)smem;            // [4 gates][32 px][68] f32 = 34816 B
    const int gate = w >> 1;
    const int chalf = (w & 1) * 32;

    float bv[2];
    bv[0] = bias[w * 32 + p0];
    bv[1] = bias[w * 32 + 16 + p0];

    #pragma unroll
    for (int mf = 0; mf < 2; ++mf)
        #pragma unroll
        for (int nf = 0; nf < 2; ++nf)
            #pragma unroll
            for (int j = 0; j < 4; ++j) {
                float v = acc[mf][nf][j] + bv[nf];
                v = (gate == 2) ? tanhf(v) : hsig(v);   // gate order i,f,g,o
                const int px = mf * 16 + g * 4 + j;
                gbuf[(gate * 32 + px) * 68 + chalf + nf * 16 + p0] = v;
            }
    __syncthreads();

    // ---- state update + BN output: thread -> (pixel, 4 channels) ----
    const int p  = tid >> 4;
    const int c4 = (tid & 15) * 4;
    const float4 iv = *(const float4*)&gbuf[(0 * 32 + p) * 68 + c4];
    const float4 fv = *(const float4*)&gbuf[(1 * 32 + p) * 68 + c4];
    const float4 gv = *(const float4*)&gbuf[(2 * 32 + p) * 68 + c4];
    const float4 ov = *(const float4*)&gbuf[(3 * 32 + p) * 68 + c4];
    const size_t gpix = (size_t)((n * 64 + y) * 64 + xh * 32 + p);
    const size_t sb = gpix * 64 + c4;
    const float4 cold = *(const float4*)&cbuf[sb];
    const float4 scv  = *(const float4*)&bn[c4];
    const float4 shv  = *(const float4*)&bn[64 + c4];

    const float ivv[4] = {iv.x, iv.y, iv.z, iv.w};
    const float fvv[4] = {fv.x, fv.y, fv.z, fv.w};
    const float gvv[4] = {gv.x, gv.y, gv.z, gv.w};
    const float ovv[4] = {ov.x, ov.y, ov.z, ov.w};
    const float cov[4] = {cold.x, cold.y, cold.z, cold.w};
    const float scc[4] = {scv.x, scv.y, scv.z, scv.w};
    const float shh[4] = {shv.x, shv.y, shv.z, shv.w};

    float cnew[4], obuf[4];
    us4 hh;
    unsigned short* hhp = (unsigned short*)&hh;
    #pragma unroll
    for (int j = 0; j < 4; ++j) {
        const float cn = fvv[j] * cov[j] + ivv[j] * gvv[j];
        const float hn = ovv[j] * tanhf(cn);
        cnew[j] = cn;
        hhp[j] = f2h(hn);
        obuf[j] = hn * scc[j] + shh[j];
    }
    *(float4*)&cbuf[sb] = *(float4*)&cnew[0];
    *(us4*)&ho[sb]      = hh;
    const size_t ob = ((size_t)((n * TT + t) * 4096 + y * 64 + xh * 32 + p)) * 64 + c4;
    *(float4*)&out[ob] = *(float4*)&obuf[0];
}

extern "C" void kernel_launch(void* const* d_in, const int* in_sizes, int n_in,
                              void* d_out, int out_size, void* d_ws, size_t ws_size,
                              hipStream_t stream) {
    const float* x     = (const float*)d_in[0];
    const float* Wx    = (const float*)d_in[1];
    const float* Wh    = (const float*)d_in[2];
    const float* b     = (const float*)d_in[3];
    const float* gamma = (const float*)d_in[4];
    const float* beta  = (const float*)d_in[5];
    const float* mean  = (const float*)d_in[6];
    const float* var   = (const float*)d_in[7];
    float* out = (float*)d_out;
    char* ws = (char*)d_ws;

    unsigned short* Wc   = (unsigned short*)(ws);            // 589,824 B
    float*          bn   = (float*)(ws + 589824);            // 512 B
    unsigned short* hA   = (unsigned short*)(ws + 590336);   // 1 MB fp16
    float*          cbuf = (float*)(ws + 1638912);           // 2 MB fp32
    unsigned short* hB   = (unsigned short*)(ws + 3736064);  // 1 MB fp16

    // zero h0 (hA) + c0 (cbuf) — contiguous 3 MB
    hipMemsetAsync(ws + 590336, 0, 3145728, stream);
    prep_kernel<<<1153, 256, 0, stream>>>(Wx, Wh, gamma, beta, mean, var, Wc, bn);

    for (int t = 0; t < TT; ++t) {
        const bool even = (t & 1) == 0;
        convstep_kernel<<<256, 512, 0, stream>>>(
            x,
            even ? hA : hB,
            Wc, b, cbuf,
            even ? hB : hA,
            bn, out, t);
    }
}

// Round 9
// 212.490 us; speedup vs baseline: 9.5063x; 1.0192x over previous
//
#include <hip/hip_runtime.h>
#include <cstddef>

typedef __attribute__((ext_vector_type(8))) _Float16 half8;
typedef __attribute__((ext_vector_type(4))) float f32x4;
typedef __attribute__((ext_vector_type(4))) unsigned short us4;

#define TT 16
#define APAD 72                 // shorts per (row,col) slot: 144 B
#define A_TILE (3*34*APAD)      // step-kernel tile: 7344 shorts
#define XA_TILE (3*66*APAD)     // xconv-kernel tile: 14256 shorts
#define CHUNK  8192             // shorts per 16KB weight chunk
#define NBUF   6
#define PFDIST 5                // MUST be < NBUF (buffer-reuse race)

__device__ __forceinline__ unsigned short f2h(float f) {
    return __builtin_bit_cast(unsigned short, (_Float16)f);
}
__device__ __forceinline__ float h2f(unsigned short u) {
    return (float)__builtin_bit_cast(_Float16, u);
}
__device__ __forceinline__ float hsig(float z) {
    return fminf(fmaxf(0.2f * z + 0.5f, 0.f), 1.f);
}

typedef __attribute__((address_space(3))) unsigned int lds_uint;
typedef const __attribute__((address_space(1))) unsigned int glb_uint;
__device__ __forceinline__ void async16(const void* g, void* l) {
    __builtin_amdgcn_global_load_lds((glb_uint*)g, (lds_uint*)l, 16, 0, 0);
}

#define WAITVM(N) { asm volatile("s_waitcnt vmcnt(" #N ")" ::: "memory"); \
                    __builtin_amdgcn_sched_barrier(0); }

// Weight pack (fp16): Wc short idx i = (s*4 + kg)*2048 + n*8 + j, s in [0,36)
// s<18 -> Wx chunk sub=s ; s>=18 -> Wh chunk sub=s-18
__global__ __launch_bounds__(256) void prep_kernel(
    const float* __restrict__ Wx, const float* __restrict__ Wh,
    const float* __restrict__ gamma, const float* __restrict__ beta,
    const float* __restrict__ mean, const float* __restrict__ var,
    unsigned short* __restrict__ Wc, float* __restrict__ bn)
{
    if (blockIdx.x == 1152) {
        if (threadIdx.x < 64) {
            const int c = threadIdx.x;
            const float inv = gamma[c] * rsqrtf(var[c] + 1e-3f);
            bn[c] = inv;
            bn[64 + c] = beta[c] - mean[c] * inv;
        }
        return;
    }
    const int i = blockIdx.x * 256 + threadIdx.x;   // < 294912
    const int j  = i & 7;
    const int n  = (i >> 3) & 255;
    const int kg = (i >> 11) & 3;
    const int s  = i >> 13;            // 0..35
    const int sub = s % 18;
    const float* W = (s >= 18) ? Wh : Wx;
    const int k5 = sub * 32 + kg * 8 + j;
    const int c = k5 & 63, q = k5 >> 6;
    const int kx = q % 3, ky = q / 3;
    Wc[i] = f2h(W[(size_t)((ky * 3 + kx) * 64 + c) * 256 + n]);
}

// 18-chunk conv pass (shared by both kernels). Chunk indices C0..C0+17; prefetch
// continues through chunk CLAST. A tile at byte-offset AOFF (shorts).
template<int C0, int CLAST, int AOFF>
__device__ __forceinline__ void conv_pass18(
    const unsigned short* __restrict__ Wc,
    const int soff0, const int soff1,
    unsigned short* lds0, unsigned short* lds1,
    const unsigned short* abase,
    const unsigned short* bbase,
    f32x4 acc[2][2])
{
    #pragma unroll
    for (int sub = 0; sub < 18; ++sub) {
        const int ci = C0 + sub;
        if (ci + PFDIST <= CLAST) {
            const int sc = ci + PFDIST;
            const unsigned short* gsc = Wc + (size_t)sc * CHUNK;
            const int bsel = (sc % NBUF) * CHUNK;
            async16(gsc + soff0, lds0 + bsel);
            async16(gsc + soff1, lds1 + bsel);
        }
        const int rem = CLAST - ci;
        if (rem >= PFDIST) WAITVM(10)
        else if (rem == 4) WAITVM(8)
        else if (rem == 3) WAITVM(6)
        else if (rem == 2) WAITVM(4)
        else if (rem == 1) WAITVM(2)
        else               WAITVM(0)

        const int ky = sub / 6, kx = (sub / 2) % 3, cb = sub & 1;
        const int aimm = (ky * 34 + kx) * APAD + cb * 32;
        const unsigned short* bbuf = bbase + (ci % NBUF) * CHUNK;

        const half8 b0 = *(const half8*)(bbuf);
        const half8 b1 = *(const half8*)(bbuf + 128);
        const unsigned short* at = abase + AOFF + aimm;
        const half8 a0 = *(const half8*)(at);
        const half8 a1 = *(const half8*)(at + 16 * APAD);
        acc[0][0] = __builtin_amdgcn_mfma_f32_16x16x32_f16(a0, b0, acc[0][0], 0, 0, 0);
        acc[0][1] = __builtin_amdgcn_mfma_f32_16x16x32_f16(a0, b1, acc[0][1], 0, 0, 0);
        acc[1][0] = __builtin_amdgcn_mfma_f32_16x16x32_f16(a1, b0, acc[1][0], 0, 0, 0);
        acc[1][1] = __builtin_amdgcn_mfma_f32_16x16x32_f16(a1, b1, acc[1][1], 0, 0, 0);
    }
}

// Hoisted x-conv: xg[b,t,y,px][ch] = conv(x_t, Wx) + bias, fp16.
// Block = (n,t,y): full 64-px row x 256 ch. Grid 2048.
__global__ __launch_bounds__(512) void xconv_kernel(
    const float* __restrict__ x,
    const unsigned short* __restrict__ Wc,
    const float* __restrict__ bias,
    unsigned short* __restrict__ xg)
{
    const int bid = blockIdx.x;
    const int y = bid & 63;
    const int t = (bid >> 6) & 15;
    const int n = bid >> 10;
    const int tid = threadIdx.x, lane = tid & 63, w = tid >> 6;

    __shared__ __align__(16) unsigned short smem[XA_TILE + NBUF * CHUNK];

    // prologue weight staging FIRST (DMA overlaps A-stage loads)
    const int soff0 = ((lane >> 5)    ) * 2048 + (w * 32 + (lane & 31)) * 8;
    const int soff1 = ((lane >> 5) + 2) * 2048 + (w * 32 + (lane & 31)) * 8;
    unsigned short* lds0 = smem + XA_TILE + w * 1024 + (lane     ) * 8;
    unsigned short* lds1 = smem + XA_TILE + w * 1024 + (64 + lane) * 8;
    #pragma unroll
    for (int sc = 0; sc < PFDIST; ++sc) {
        const unsigned short* gsc = Wc + (size_t)sc * CHUNK;
        async16(gsc + soff0, lds0 + sc * CHUNK);
        async16(gsc + soff1, lds1 + sc * CHUNK);
    }

    // A tile: [3][66][APAD] fp16 from x f32
    const float* __restrict__ xt = x + (size_t)(n * TT + t) * 4096 * 64;
    for (int idx = tid; idx < 3 * 66 * 8; idx += 512) {
        const int cg  = idx & 7;
        const int col = (idx >> 3) % 66;
        const int r   = (idx >> 3) / 66;
        const int gy = y + r - 1;
        const int gx = col - 1;
        const bool ok = ((unsigned)gy < 64u) && ((unsigned)gx < 64u);
        float4 v0 = make_float4(0.f, 0.f, 0.f, 0.f), v1 = v0;
        if (ok) {
            const float* p = xt + (size_t)(gy * 64 + gx) * 64 + cg * 8;
            v0 = *(const float4*)p;
            v1 = *(const float4*)(p + 4);
        }
        us4 h0, h1;
        h0.x = f2h(v0.x); h0.y = f2h(v0.y); h0.z = f2h(v0.z); h0.w = f2h(v0.w);
        h1.x = f2h(v1.x); h1.y = f2h(v1.y); h1.z = f2h(v1.z); h1.w = f2h(v1.w);
        const int ebase = (r * 66 + col) * APAD + cg * 8;
        *(us4*)&smem[ebase]     = h0;
        *(us4*)&smem[ebase + 4] = h1;
    }
    __syncthreads();

    const int p0 = lane & 15, g = lane >> 4;
    const unsigned short* abase = smem + p0 * APAD + g * 8;
    const unsigned short* bbase = smem + XA_TILE + w * 1024 + (g * 32 + p0) * 8;

    f32x4 acc[4][2] = {};
    #pragma unroll
    for (int sub = 0; sub < 18; ++sub) {
        if (sub + PFDIST < 18) {
            const int sc = sub + PFDIST;
            const unsigned short* gsc = Wc + (size_t)sc * CHUNK;
            const int bsel = (sc % NBUF) * CHUNK;
            async16(gsc + soff0, lds0 + bsel);
            async16(gsc + soff1, lds1 + bsel);
        }
        const int rem = 17 - sub;
        if (rem >= PFDIST) WAITVM(10)
        else if (rem == 4) WAITVM(8)
        else if (rem == 3) WAITVM(6)
        else if (rem == 2) WAITVM(4)
        else if (rem == 1) WAITVM(2)
        else               WAITVM(0)

        const int ky = sub / 6, kx = (sub / 2) % 3, cb = sub & 1;
        const unsigned short* bbuf = bbase + (sub % NBUF) * CHUNK;
        const half8 b0 = *(const half8*)(bbuf);
        const half8 b1 = *(const half8*)(bbuf + 128);
        #pragma unroll
        for (int mf = 0; mf < 4; ++mf) {
            const half8 a = *(const half8*)(abase + (ky * 66 + kx + mf * 16) * APAD + cb * 32);
            acc[mf][0] = __builtin_amdgcn_mfma_f32_16x16x32_f16(a, b0, acc[mf][0], 0, 0, 0);
            acc[mf][1] = __builtin_amdgcn_mfma_f32_16x16x32_f16(a, b1, acc[mf][1], 0, 0, 0);
        }
    }

    // write xg (+bias), fp16. 16 lanes p0=0..15 -> 16 consecutive ch = 32B/store-group
    const size_t obase = ((size_t)((n * TT + t) * 4096 + y * 64)) * 256;
    const float bv0 = bias[w * 32 + p0];
    const float bv1 = bias[w * 32 + 16 + p0];
    #pragma unroll
    for (int mf = 0; mf < 4; ++mf)
        #pragma unroll
        for (int nf = 0; nf < 2; ++nf) {
            const float bv = nf ? bv1 : bv0;
            #pragma unroll
            for (int j = 0; j < 4; ++j) {
                const int px = mf * 16 + g * 4 + j;
                xg[obase + (size_t)px * 256 + w * 32 + nf * 16 + p0] = f2h(acc[mf][nf][j] + bv);
            }
        }
}

// Per-timestep kernel. FUSED=1: full x+h conv (round-8 behavior, ws fallback).
// FUSED=0: h-conv only + xg read. Block = (n,y,xhalf): 32 px x 256 ch, 8 waves.
template<int FUSED>
__global__ __launch_bounds__(512) void convstep_kernel(
    const float* __restrict__ x,
    const unsigned short* __restrict__ hb,
    const unsigned short* __restrict__ Wc,
    const float* __restrict__ bias,
    const unsigned short* __restrict__ xg,
    float* __restrict__ cbuf,
    unsigned short* __restrict__ ho,
    const float* __restrict__ bn,
    float* __restrict__ out,
    const int t)
{
    const int bid0 = blockIdx.x;
    const int bid = (bid0 & 7) * 32 + (bid0 >> 3);   // bijective XCD swizzle
    const int xh = bid & 1;
    const int y  = (bid >> 1) & 63;
    const int n  = bid >> 7;
    const int tid = threadIdx.x;
    const int lane = tid & 63;
    const int w = tid >> 6;
    const int p0 = lane & 15;
    const int g  = lane >> 4;

    constexpr int NTILE = FUSED ? 2 : 1;
    constexpr int BOFF  = NTILE * A_TILE;
    __shared__ __align__(16) unsigned short smem[NTILE * A_TILE + NBUF * CHUNK];

    // xg prefetch into VGPRs (FUSED=0): independent of everything, hides under K-loop
    unsigned short xgv[2][2][4];
    if (!FUSED) {
        const size_t xb = ((size_t)((n * TT + t) * 4096 + y * 64 + xh * 32)) * 256 + w * 32;
        #pragma unroll
        for (int mf = 0; mf < 2; ++mf)
            #pragma unroll
            for (int nf = 0; nf < 2; ++nf)
                #pragma unroll
                for (int j = 0; j < 4; ++j)
                    xgv[mf][nf][j] = xg[xb + (size_t)(mf * 16 + g * 4 + j) * 256 + nf * 16 + p0];
    }

    // prologue weight staging FIRST (DMA overlaps A-stage)
    constexpr int C0 = FUSED ? 0 : 18;    // 18 % NBUF == 0: buffer phasing identical
    const int soff0 = ((lane >> 5)    ) * 2048 + (w * 32 + (lane & 31)) * 8;
    const int soff1 = ((lane >> 5) + 2) * 2048 + (w * 32 + (lane & 31)) * 8;
    unsigned short* lds0 = smem + BOFF + w * 1024 + (lane     ) * 8;
    unsigned short* lds1 = smem + BOFF + w * 1024 + (64 + lane) * 8;
    #pragma unroll
    for (int sc = C0; sc < C0 + PFDIST; ++sc) {
        const unsigned short* gsc = Wc + (size_t)sc * CHUNK;
        async16(gsc + soff0, lds0 + (sc % NBUF) * CHUNK);
        async16(gsc + soff1, lds1 + (sc % NBUF) * CHUNK);
    }

    // ---- stage A tiles: FUSED: x(tile0) + h(tile1); else h(tile0) ----
    const float* __restrict__ xt = x + (size_t)(n * TT + t) * 4096 * 64;
    const size_t hbase = (size_t)n * 4096 * 64;
    for (int idx = tid; idx < NTILE * 3 * 34 * 8; idx += 512) {
        const int cg  = idx & 7;
        const int col = (idx >> 3) % 34;
        const int i3  = (idx >> 3) / 34;
        const int r   = i3 % 3;
        const int src = i3 / 3;
        const int gy = y + r - 1;
        const int gx = xh * 32 + col - 1;
        const bool ok = ((unsigned)gy < 64u) && ((unsigned)gx < 64u);
        const int ebase = (r * 34 + col) * APAD + cg * 8;
        if (FUSED && src == 0) {
            float4 v0 = make_float4(0.f, 0.f, 0.f, 0.f), v1 = v0;
            if (ok) {
                const float* p = xt + (size_t)(gy * 64 + gx) * 64 + cg * 8;
                v0 = *(const float4*)p;
                v1 = *(const float4*)(p + 4);
            }
            us4 h0, h1;
            h0.x = f2h(v0.x); h0.y = f2h(v0.y); h0.z = f2h(v0.z); h0.w = f2h(v0.w);
            h1.x = f2h(v1.x); h1.y = f2h(v1.y); h1.z = f2h(v1.z); h1.w = f2h(v1.w);
            *(us4*)&smem[ebase]     = h0;
            *(us4*)&smem[ebase + 4] = h1;
        } else {
            uint4 v = make_uint4(0u, 0u, 0u, 0u);
            if (ok) v = *(const uint4*)(hb + hbase + (size_t)(gy * 64 + gx) * 64 + cg * 8);
            *(uint4*)&smem[(FUSED ? A_TILE : 0) + ebase] = v;
        }
    }
    __syncthreads();   // drains vmcnt(0): A tiles + prologue chunks valid

    // ---- K-loop ----
    const unsigned short* abase = smem + p0 * APAD + g * 8;
    const unsigned short* bbase = smem + BOFF + w * 1024 + (g * 32 + p0) * 8;

    f32x4 acc[2][2] = {};
    if (FUSED) {
        conv_pass18<0, 35, 0>(Wc, soff0, soff1, lds0, lds1, abase, bbase, acc);
        conv_pass18<18, 35, A_TILE>(Wc, soff0, soff1, lds0, lds1, abase, bbase, acc);
    } else {
        conv_pass18<18, 35, 0>(Wc, soff0, soff1, lds0, lds1, abase, bbase, acc);
    }

    // ---- gates -> LDS gate buffer (overlay; all chunk reads done) ----
    __syncthreads();
    float* gbuf = (float*)smem;            // [4][32][68] f32 = 34816 B (fits both variants)
    const int gate = w >> 1;
    const int chalf = (w & 1) * 32;

    float bv[2];
    bv[0] = bias[w * 32 + p0];
    bv[1] = bias[w * 32 + 16 + p0];

    #pragma unroll
    for (int mf = 0; mf < 2; ++mf)
        #pragma unroll
        for (int nf = 0; nf < 2; ++nf)
            #pragma unroll
            for (int j = 0; j < 4; ++j) {
                float v = acc[mf][nf][j] + (FUSED ? bv[nf] : h2f(xgv[mf][nf][j]));
                v = (gate == 2) ? tanhf(v) : hsig(v);   // gate order i,f,g,o
                const int px = mf * 16 + g * 4 + j;
                gbuf[(gate * 32 + px) * 68 + chalf + nf * 16 + p0] = v;
            }
    __syncthreads();

    // ---- state update + BN output ----
    const int p  = tid >> 4;
    const int c4 = (tid & 15) * 4;
    const float4 iv = *(const float4*)&gbuf[(0 * 32 + p) * 68 + c4];
    const float4 fv = *(const float4*)&gbuf[(1 * 32 + p) * 68 + c4];
    const float4 gv = *(const float4*)&gbuf[(2 * 32 + p) * 68 + c4];
    const float4 ov = *(const float4*)&gbuf[(3 * 32 + p) * 68 + c4];
    const size_t gpix = (size_t)((n * 64 + y) * 64 + xh * 32 + p);
    const size_t sb = gpix * 64 + c4;
    const float4 cold = *(const float4*)&cbuf[sb];
    const float4 scv  = *(const float4*)&bn[c4];
    const float4 shv  = *(const float4*)&bn[64 + c4];

    const float ivv[4] = {iv.x, iv.y, iv.z, iv.w};
    const float fvv[4] = {fv.x, fv.y, fv.z, fv.w};
    const float gvv[4] = {gv.x, gv.y, gv.z, gv.w};
    const float ovv[4] = {ov.x, ov.y, ov.z, ov.w};
    const float cov[4] = {cold.x, cold.y, cold.z, cold.w};
    const float scc[4] = {scv.x, scv.y, scv.z, scv.w};
    const float shh[4] = {shv.x, shv.y, shv.z, shv.w};

    float cnew[4], obuf[4];
    us4 hh;
    unsigned short* hhp = (unsigned short*)&hh;
    #pragma unroll
    for (int j = 0; j < 4; ++j) {
        const float cn = fvv[j] * cov[j] + ivv[j] * gvv[j];
        const float hn = ovv[j] * tanhf(cn);
        cnew[j] = cn;
        hhp[j] = f2h(hn);
        obuf[j] = hn * scc[j] + shh[j];
    }
    *(float4*)&cbuf[sb] = *(float4*)&cnew[0];
    *(us4*)&ho[sb]      = hh;
    const size_t ob = ((size_t)((n * TT + t) * 4096 + y * 64 + xh * 32 + p)) * 64 + c4;
    *(float4*)&out[ob] = *(float4*)&obuf[0];
}

extern "C" void kernel_launch(void* const* d_in, const int* in_sizes, int n_in,
                              void* d_out, int out_size, void* d_ws, size_t ws_size,
                              hipStream_t stream) {
    const float* x     = (const float*)d_in[0];
    const float* Wx    = (const float*)d_in[1];
    const float* Wh    = (const float*)d_in[2];
    const float* b     = (const float*)d_in[3];
    const float* gamma = (const float*)d_in[4];
    const float* beta  = (const float*)d_in[5];
    const float* mean  = (const float*)d_in[6];
    const float* var   = (const float*)d_in[7];
    float* out = (float*)d_out;
    char* ws = (char*)d_ws;

    unsigned short* Wc   = (unsigned short*)(ws);            // 589,824 B
    float*          bn   = (float*)(ws + 589824);            // 512 B
    unsigned short* hA   = (unsigned short*)(ws + 590336);   // 1 MB fp16
    float*          cbuf = (float*)(ws + 1638912);           // 2 MB fp32
    unsigned short* hB   = (unsigned short*)(ws + 3736064);  // 1 MB fp16
    unsigned short* xg   = (unsigned short*)(ws + 4784640);  // 67,108,864 B
    const size_t NEED = 4784640ull + 67108864ull;            // 71,893,504 B

    hipMemsetAsync(ws + 590336, 0, 3145728, stream);         // h0 + c0 = 0
    prep_kernel<<<1153, 256, 0, stream>>>(Wx, Wh, gamma, beta, mean, var, Wc, bn);

    if (ws_size >= NEED) {
        xconv_kernel<<<2048, 512, 0, stream>>>(x, Wc, b, xg);
        for (int t = 0; t < TT; ++t) {
            const bool even = (t & 1) == 0;
            convstep_kernel<0><<<256, 512, 0, stream>>>(
                x, even ? hA : hB, Wc, b, xg, cbuf, even ? hB : hA, bn, out, t);
        }
    } else {
        for (int t = 0; t < TT; ++t) {
            const bool even = (t & 1) == 0;
            convstep_kernel<1><<<256, 512, 0, stream>>>(
                x, even ? hA : hB, Wc, b, xg, cbuf, even ? hB : hA, bn, out, t);
        }
    }
}

// Round 10
// 206.493 us; speedup vs baseline: 9.7824x; 1.0290x over previous
//
#include <hip/hip_runtime.h>
#include <cstddef>

typedef __attribute__((ext_vector_type(8))) _Float16 half8;
typedef __attribute__((ext_vector_type(4))) float f32x4;
typedef __attribute__((ext_vector_type(4))) unsigned short us4;

#define TT 16
#define APAD 72                 // shorts per (row,col) slot: 144 B
#define A_TILE (3*34*APAD)      // step-kernel tile: 7344 shorts
#define XA_TILE (3*66*APAD)     // xconv-kernel tile: 14256 shorts
#define CHUNK  8192             // shorts per 16KB weight chunk
#define NBUF   6
#define PFDIST 5                // MUST be < NBUF (buffer-reuse race)

__device__ __forceinline__ unsigned short f2h(float f) {
    return __builtin_bit_cast(unsigned short, (_Float16)f);
}
__device__ __forceinline__ float h2f(unsigned short u) {
    return (float)__builtin_bit_cast(_Float16, u);
}
__device__ __forceinline__ float hsig(float z) {
    return fminf(fmaxf(0.2f * z + 0.5f, 0.f), 1.f);
}

typedef __attribute__((address_space(3))) unsigned int lds_uint;
typedef const __attribute__((address_space(1))) unsigned int glb_uint;
__device__ __forceinline__ void async16(const void* g, void* l) {
    __builtin_amdgcn_global_load_lds((glb_uint*)g, (lds_uint*)l, 16, 0, 0);
}

#define WAITVM(N) { asm volatile("s_waitcnt vmcnt(" #N ")" ::: "memory"); \
                    __builtin_amdgcn_sched_barrier(0); }

// Weight pack (fp16): Wc short idx i = (s*4 + kg)*2048 + n*8 + j, s in [0,36)
// s<18 -> Wx chunk sub=s ; s>=18 -> Wh chunk sub=s-18
__global__ __launch_bounds__(256) void prep_kernel(
    const float* __restrict__ Wx, const float* __restrict__ Wh,
    const float* __restrict__ gamma, const float* __restrict__ beta,
    const float* __restrict__ mean, const float* __restrict__ var,
    unsigned short* __restrict__ Wc, float* __restrict__ bn)
{
    if (blockIdx.x == 1152) {
        if (threadIdx.x < 64) {
            const int c = threadIdx.x;
            const float inv = gamma[c] * rsqrtf(var[c] + 1e-3f);
            bn[c] = inv;
            bn[64 + c] = beta[c] - mean[c] * inv;
        }
        return;
    }
    const int i = blockIdx.x * 256 + threadIdx.x;   // < 294912
    const int j  = i & 7;
    const int n  = (i >> 3) & 255;
    const int kg = (i >> 11) & 3;
    const int s  = i >> 13;            // 0..35
    const int sub = s % 18;
    const float* W = (s >= 18) ? Wh : Wx;
    const int k5 = sub * 32 + kg * 8 + j;
    const int c = k5 & 63, q = k5 >> 6;
    const int kx = q % 3, ky = q / 3;
    Wc[i] = f2h(W[(size_t)((ky * 3 + kx) * 64 + c) * 256 + n]);
}

// 18-chunk conv pass (step kernel). Chunk indices C0..C0+17; prefetch through CLAST.
template<int C0, int CLAST, int AOFF>
__device__ __forceinline__ void conv_pass18(
    const unsigned short* __restrict__ Wc,
    const int soff0, const int soff1,
    unsigned short* lds0, unsigned short* lds1,
    const unsigned short* abase,
    const unsigned short* bbase,
    f32x4 acc[2][2])
{
    #pragma unroll
    for (int sub = 0; sub < 18; ++sub) {
        const int ci = C0 + sub;
        if (ci + PFDIST <= CLAST) {
            const int sc = ci + PFDIST;
            const unsigned short* gsc = Wc + (size_t)sc * CHUNK;
            const int bsel = (sc % NBUF) * CHUNK;
            async16(gsc + soff0, lds0 + bsel);
            async16(gsc + soff1, lds1 + bsel);
        }
        const int rem = CLAST - ci;
        if (rem >= PFDIST) WAITVM(10)
        else if (rem == 4) WAITVM(8)
        else if (rem == 3) WAITVM(6)
        else if (rem == 2) WAITVM(4)
        else if (rem == 1) WAITVM(2)
        else               WAITVM(0)

        const int ky = sub / 6, kx = (sub / 2) % 3, cb = sub & 1;
        const int aimm = (ky * 34 + kx) * APAD + cb * 32;
        const unsigned short* bbuf = bbase + (ci % NBUF) * CHUNK;

        const half8 b0 = *(const half8*)(bbuf);
        const half8 b1 = *(const half8*)(bbuf + 128);
        const unsigned short* at = abase + AOFF + aimm;
        const half8 a0 = *(const half8*)(at);
        const half8 a1 = *(const half8*)(at + 16 * APAD);
        acc[0][0] = __builtin_amdgcn_mfma_f32_16x16x32_f16(a0, b0, acc[0][0], 0, 0, 0);
        acc[0][1] = __builtin_amdgcn_mfma_f32_16x16x32_f16(a0, b1, acc[0][1], 0, 0, 0);
        acc[1][0] = __builtin_amdgcn_mfma_f32_16x16x32_f16(a1, b0, acc[1][0], 0, 0, 0);
        acc[1][1] = __builtin_amdgcn_mfma_f32_16x16x32_f16(a1, b1, acc[1][1], 0, 0, 0);
    }
}

// Hoisted x-conv: xg = conv(x_t, Wx) + bias, fp16, BLOCKED consumer layout:
// vector-record vi = ((((n*16+t)*64+y)*2+xh)*8+w)*64+lane, 16 shorts [mf][nf][j].
// Block = (n,t,y): full 64-px row x 256 ch. Grid 2048, XCD-swizzled.
__global__ __launch_bounds__(512) void xconv_kernel(
    const float* __restrict__ x,
    const unsigned short* __restrict__ Wc,
    const float* __restrict__ bias,
    unsigned short* __restrict__ xg)
{
    const int bid0 = blockIdx.x;
    const int bid = (bid0 & 7) * 256 + (bid0 >> 3);  // bijective: XCD owns (t,y)-slabs
    const int y = bid & 63;
    const int t = (bid >> 6) & 15;
    const int n = bid >> 10;
    const int tid = threadIdx.x, lane = tid & 63, w = tid >> 6;

    __shared__ __align__(16) unsigned short smem[XA_TILE + NBUF * CHUNK];

    // prologue weight staging FIRST (DMA overlaps A-stage loads)
    const int soff0 = ((lane >> 5)    ) * 2048 + (w * 32 + (lane & 31)) * 8;
    const int soff1 = ((lane >> 5) + 2) * 2048 + (w * 32 + (lane & 31)) * 8;
    unsigned short* lds0 = smem + XA_TILE + w * 1024 + (lane     ) * 8;
    unsigned short* lds1 = smem + XA_TILE + w * 1024 + (64 + lane) * 8;
    #pragma unroll
    for (int sc = 0; sc < PFDIST; ++sc) {
        const unsigned short* gsc = Wc + (size_t)sc * CHUNK;
        async16(gsc + soff0, lds0 + sc * CHUNK);
        async16(gsc + soff1, lds1 + sc * CHUNK);
    }

    // A tile: [3][66][APAD] fp16 from x f32
    const float* __restrict__ xt = x + (size_t)(n * TT + t) * 4096 * 64;
    for (int idx = tid; idx < 3 * 66 * 8; idx += 512) {
        const int cg  = idx & 7;
        const int col = (idx >> 3) % 66;
        const int r   = (idx >> 3) / 66;
        const int gy = y + r - 1;
        const int gx = col - 1;
        const bool ok = ((unsigned)gy < 64u) && ((unsigned)gx < 64u);
        float4 v0 = make_float4(0.f, 0.f, 0.f, 0.f), v1 = v0;
        if (ok) {
            const float* p = xt + (size_t)(gy * 64 + gx) * 64 + cg * 8;
            v0 = *(const float4*)p;
            v1 = *(const float4*)(p + 4);
        }
        us4 h0, h1;
        h0.x = f2h(v0.x); h0.y = f2h(v0.y); h0.z = f2h(v0.z); h0.w = f2h(v0.w);
        h1.x = f2h(v1.x); h1.y = f2h(v1.y); h1.z = f2h(v1.z); h1.w = f2h(v1.w);
        const int ebase = (r * 66 + col) * APAD + cg * 8;
        *(us4*)&smem[ebase]     = h0;
        *(us4*)&smem[ebase + 4] = h1;
    }
    __syncthreads();

    const int p0 = lane & 15, g = lane >> 4;
    const unsigned short* abase = smem + p0 * APAD + g * 8;
    const unsigned short* bbase = smem + XA_TILE + w * 1024 + (g * 32 + p0) * 8;

    f32x4 acc[4][2] = {};
    #pragma unroll
    for (int sub = 0; sub < 18; ++sub) {
        if (sub + PFDIST < 18) {
            const int sc = sub + PFDIST;
            const unsigned short* gsc = Wc + (size_t)sc * CHUNK;
            const int bsel = (sc % NBUF) * CHUNK;
            async16(gsc + soff0, lds0 + bsel);
            async16(gsc + soff1, lds1 + bsel);
        }
        const int rem = 17 - sub;
        if (rem >= PFDIST) WAITVM(10)
        else if (rem == 4) WAITVM(8)
        else if (rem == 3) WAITVM(6)
        else if (rem == 2) WAITVM(4)
        else if (rem == 1) WAITVM(2)
        else               WAITVM(0)

        const int ky = sub / 6, kx = (sub / 2) % 3, cb = sub & 1;
        const unsigned short* bbuf = bbase + (sub % NBUF) * CHUNK;
        const half8 b0 = *(const half8*)(bbuf);
        const half8 b1 = *(const half8*)(bbuf + 128);
        #pragma unroll
        for (int mf = 0; mf < 4; ++mf) {
            const half8 a = *(const half8*)(abase + (ky * 66 + kx + mf * 16) * APAD + cb * 32);
            acc[mf][0] = __builtin_amdgcn_mfma_f32_16x16x32_f16(a, b0, acc[mf][0], 0, 0, 0);
            acc[mf][1] = __builtin_amdgcn_mfma_f32_16x16x32_f16(a, b1, acc[mf][1], 0, 0, 0);
        }
    }

    // packed xg store: per lane, per xh: 16 shorts = 2 x uint4 (was 32 x 2B scatter)
    const float bv0 = bias[w * 32 + p0];
    const float bv1 = bias[w * 32 + 16 + p0];
    const size_t vibase = ((((size_t)(n * TT + t) * 64 + y) * 2) * 8 + w) * 64 + lane;
    #pragma unroll
    for (int xh2 = 0; xh2 < 2; ++xh2) {
        unsigned short os[16];
        #pragma unroll
        for (int mfc = 0; mfc < 2; ++mfc)
            #pragma unroll
            for (int nf = 0; nf < 2; ++nf)
                #pragma unroll
                for (int j = 0; j < 4; ++j)
                    os[mfc * 8 + nf * 4 + j] =
                        f2h(acc[xh2 * 2 + mfc][nf][j] + (nf ? bv1 : bv0));
        unsigned short* dst = xg + (vibase + (size_t)xh2 * 512) * 16;
        *(uint4*)dst       = *(uint4*)&os[0];
        *(uint4*)(dst + 8) = *(uint4*)&os[8];
    }
}

// Per-timestep kernel. FUSED=1: full x+h conv (ws fallback). FUSED=0: h-conv + xg.
// Block = (n,y,xhalf): 32 px x 256 ch, 8 waves.
template<int FUSED>
__global__ __launch_bounds__(512) void convstep_kernel(
    const float* __restrict__ x,
    const unsigned short* __restrict__ hb,
    const unsigned short* __restrict__ Wc,
    const float* __restrict__ bias,
    const unsigned short* __restrict__ xg,
    float* __restrict__ cbuf,
    unsigned short* __restrict__ ho,
    const float* __restrict__ bn,
    float* __restrict__ out,
    const int t)
{
    const int bid0 = blockIdx.x;
    const int bid = (bid0 & 7) * 32 + (bid0 >> 3);   // bijective XCD swizzle
    const int xh = bid & 1;
    const int y  = (bid >> 1) & 63;
    const int n  = bid >> 7;
    const int tid = threadIdx.x;
    const int lane = tid & 63;
    const int w = tid >> 6;
    const int p0 = lane & 15;
    const int g  = lane >> 4;

    constexpr int NTILE = FUSED ? 2 : 1;
    constexpr int BOFF  = NTILE * A_TILE;
    __shared__ __align__(16) unsigned short smem[NTILE * A_TILE + NBUF * CHUNK];

    // packed xg prefetch: one 32B record per lane (2 x uint4) — registers only
    unsigned short xs[16];
    if (!FUSED) {
        const size_t vi = ((((size_t)(n * TT + t) * 64 + y) * 2 + xh) * 8 + w) * 64 + lane;
        const uint4* xp = (const uint4*)(xg + vi * 16);
        *(uint4*)&xs[0] = xp[0];
        *(uint4*)&xs[8] = xp[1];
    }

    // prologue weight staging FIRST (DMA overlaps A-stage)
    constexpr int C0 = FUSED ? 0 : 18;    // 18 % NBUF == 0: buffer phasing identical
    const int soff0 = ((lane >> 5)    ) * 2048 + (w * 32 + (lane & 31)) * 8;
    const int soff1 = ((lane >> 5) + 2) * 2048 + (w * 32 + (lane & 31)) * 8;
    unsigned short* lds0 = smem + BOFF + w * 1024 + (lane     ) * 8;
    unsigned short* lds1 = smem + BOFF + w * 1024 + (64 + lane) * 8;
    #pragma unroll
    for (int sc = C0; sc < C0 + PFDIST; ++sc) {
        const unsigned short* gsc = Wc + (size_t)sc * CHUNK;
        async16(gsc + soff0, lds0 + (sc % NBUF) * CHUNK);
        async16(gsc + soff1, lds1 + (sc % NBUF) * CHUNK);
    }

    // ---- stage A tiles: FUSED: x(tile0) + h(tile1); else h(tile0) ----
    const float* __restrict__ xt = x + (size_t)(n * TT + t) * 4096 * 64;
    const size_t hbase = (size_t)n * 4096 * 64;
    for (int idx = tid; idx < NTILE * 3 * 34 * 8; idx += 512) {
        const int cg  = idx & 7;
        const int col = (idx >> 3) % 34;
        const int i3  = (idx >> 3) / 34;
        const int r   = i3 % 3;
        const int src = i3 / 3;
        const int gy = y + r - 1;
        const int gx = xh * 32 + col - 1;
        const bool ok = ((unsigned)gy < 64u) && ((unsigned)gx < 64u);
        const int ebase = (r * 34 + col) * APAD + cg * 8;
        if (FUSED && src == 0) {
            float4 v0 = make_float4(0.f, 0.f, 0.f, 0.f), v1 = v0;
            if (ok) {
                const float* p = xt + (size_t)(gy * 64 + gx) * 64 + cg * 8;
                v0 = *(const float4*)p;
                v1 = *(const float4*)(p + 4);
            }
            us4 h0, h1;
            h0.x = f2h(v0.x); h0.y = f2h(v0.y); h0.z = f2h(v0.z); h0.w = f2h(v0.w);
            h1.x = f2h(v1.x); h1.y = f2h(v1.y); h1.z = f2h(v1.z); h1.w = f2h(v1.w);
            *(us4*)&smem[ebase]     = h0;
            *(us4*)&smem[ebase + 4] = h1;
        } else {
            uint4 v = make_uint4(0u, 0u, 0u, 0u);
            if (ok) v = *(const uint4*)(hb + hbase + (size_t)(gy * 64 + gx) * 64 + cg * 8);
            *(uint4*)&smem[(FUSED ? A_TILE : 0) + ebase] = v;
        }
    }
    __syncthreads();   // drains vmcnt(0): A tiles + prologue chunks + xg regs valid

    // ---- K-loop ----
    const unsigned short* abase = smem + p0 * APAD + g * 8;
    const unsigned short* bbase = smem + BOFF + w * 1024 + (g * 32 + p0) * 8;

    f32x4 acc[2][2] = {};
    if (FUSED) {
        conv_pass18<0, 35, 0>(Wc, soff0, soff1, lds0, lds1, abase, bbase, acc);
        conv_pass18<18, 35, A_TILE>(Wc, soff0, soff1, lds0, lds1, abase, bbase, acc);
    } else {
        conv_pass18<18, 35, 0>(Wc, soff0, soff1, lds0, lds1, abase, bbase, acc);
    }

    // ---- gates -> LDS gate buffer (overlay; all chunk reads done) ----
    __syncthreads();
    float* gbuf = (float*)smem;            // [4][32][68] f32 = 34816 B
    const int gate = w >> 1;
    const int chalf = (w & 1) * 32;

    float bv[2];
    bv[0] = bias[w * 32 + p0];
    bv[1] = bias[w * 32 + 16 + p0];

    #pragma unroll
    for (int mf = 0; mf < 2; ++mf)
        #pragma unroll
        for (int nf = 0; nf < 2; ++nf)
            #pragma unroll
            for (int j = 0; j < 4; ++j) {
                float v = acc[mf][nf][j] + (FUSED ? bv[nf] : h2f(xs[mf * 8 + nf * 4 + j]));
                v = (gate == 2) ? tanhf(v) : hsig(v);   // gate order i,f,g,o
                const int px = mf * 16 + g * 4 + j;
                gbuf[(gate * 32 + px) * 68 + chalf + nf * 16 + p0] = v;
            }
    __syncthreads();

    // ---- state update + BN output ----
    const int p  = tid >> 4;
    const int c4 = (tid & 15) * 4;
    const float4 iv = *(const float4*)&gbuf[(0 * 32 + p) * 68 + c4];
    const float4 fv = *(const float4*)&gbuf[(1 * 32 + p) * 68 + c4];
    const float4 gv = *(const float4*)&gbuf[(2 * 32 + p) * 68 + c4];
    const float4 ov = *(const float4*)&gbuf[(3 * 32 + p) * 68 + c4];
    const size_t gpix = (size_t)((n * 64 + y) * 64 + xh * 32 + p);
    const size_t sb = gpix * 64 + c4;
    const float4 cold = *(const float4*)&cbuf[sb];
    const float4 scv  = *(const float4*)&bn[c4];
    const float4 shv  = *(const float4*)&bn[64 + c4];

    const float ivv[4] = {iv.x, iv.y, iv.z, iv.w};
    const float fvv[4] = {fv.x, fv.y, fv.z, fv.w};
    const float gvv[4] = {gv.x, gv.y, gv.z, gv.w};
    const float ovv[4] = {ov.x, ov.y, ov.z, ov.w};
    const float cov[4] = {cold.x, cold.y, cold.z, cold.w};
    const float scc[4] = {scv.x, scv.y, scv.z, scv.w};
    const float shh[4] = {shv.x, shv.y, shv.z, shv.w};

    float cnew[4], obuf[4];
    us4 hh;
    unsigned short* hhp = (unsigned short*)&hh;
    #pragma unroll
    for (int j = 0; j < 4; ++j) {
        const float cn = fvv[j] * cov[j] + ivv[j] * gvv[j];
        const float hn = ovv[j] * tanhf(cn);
        cnew[j] = cn;
        hhp[j] = f2h(hn);
        obuf[j] = hn * scc[j] + shh[j];
    }
    *(float4*)&cbuf[sb] = *(float4*)&cnew[0];
    *(us4*)&ho[sb]      = hh;
    const size_t ob = ((size_t)((n * TT + t) * 4096 + y * 64 + xh * 32 + p)) * 64 + c4;
    *(float4*)&out[ob] = *(float4*)&obuf[0];
}

extern "C" void kernel_launch(void* const* d_in, const int* in_sizes, int n_in,
                              void* d_out, int out_size, void* d_ws, size_t ws_size,
                              hipStream_t stream) {
    const float* x     = (const float*)d_in[0];
    const float* Wx    = (const float*)d_in[1];
    const float* Wh    = (const float*)d_in[2];
    const float* b     = (const float*)d_in[3];
    const float* gamma = (const float*)d_in[4];
    const float* beta  = (const float*)d_in[5];
    const float* mean  = (const float*)d_in[6];
    const float* var   = (const float*)d_in[7];
    float* out = (float*)d_out;
    char* ws = (char*)d_ws;

    unsigned short* Wc   = (unsigned short*)(ws);            // 589,824 B
    float*          bn   = (float*)(ws + 589824);            // 512 B
    unsigned short* hA   = (unsigned short*)(ws + 590336);   // 1 MB fp16
    float*          cbuf = (float*)(ws + 1638912);           // 2 MB fp32
    unsigned short* hB   = (unsigned short*)(ws + 3736064);  // 1 MB fp16
    unsigned short* xg   = (unsigned short*)(ws + 4784640);  // 67,108,864 B
    const size_t NEED = 4784640ull + 67108864ull;            // 71,893,504 B

    hipMemsetAsync(ws + 590336, 0, 3145728, stream);         // h0 + c0 = 0
    prep_kernel<<<1153, 256, 0, stream>>>(Wx, Wh, gamma, beta, mean, var, Wc, bn);

    if (ws_size >= NEED) {
        xconv_kernel<<<2048, 512, 0, stream>>>(x, Wc, b, xg);
        for (int t = 0; t < TT; ++t) {
            const bool even = (t & 1) == 0;
            convstep_kernel<0><<<256, 512, 0, stream>>>(
                x, even ? hA : hB, Wc, b, xg, cbuf, even ? hB : hA, bn, out, t);
        }
    } else {
        for (int t = 0; t < TT; ++t) {
            const bool even = (t & 1) == 0;
            convstep_kernel<1><<<256, 512, 0, stream>>>(
                x, even ? hA : hB, Wc, b, xg, cbuf, even ? hB : hA, bn, out, t);
        }
    }
}

// Round 11
// 203.131 us; speedup vs baseline: 9.9443x; 1.0166x over previous
//
#include <hip/hip_runtime.h>
#include <cstddef>

typedef __attribute__((ext_vector_type(8))) _Float16 half8;
typedef __attribute__((ext_vector_type(4))) float f32x4;
typedef __attribute__((ext_vector_type(4))) unsigned short us4;

#define TT 16
#define APAD 72                 // shorts per (row,col) slot: 144 B
#define A_TILE (3*34*APAD)      // step-kernel tile: 7344 shorts
#define CHUNK  8192             // shorts per 16KB weight chunk
#define NB     6                // B reg-pipeline slots
#define PF     5                // prefetch distance (< NB)

__device__ __forceinline__ unsigned short f2h(float f) {
    return __builtin_bit_cast(unsigned short, (_Float16)f);
}
__device__ __forceinline__ float h2f(unsigned short u) {
    return (float)__builtin_bit_cast(_Float16, u);
}
__device__ __forceinline__ float hsig(float z) {
    return fminf(fmaxf(0.2f * z + 0.5f, 0.f), 1.f);
}

// Weight pack (fp16): Wc short idx i = (s*4 + kg)*2048 + n*8 + j, s in [0,36)
// s<18 -> Wx chunk sub=s ; s>=18 -> Wh chunk sub=s-18
__global__ __launch_bounds__(256) void prep_kernel(
    const float* __restrict__ Wx, const float* __restrict__ Wh,
    const float* __restrict__ gamma, const float* __restrict__ beta,
    const float* __restrict__ mean, const float* __restrict__ var,
    unsigned short* __restrict__ Wc, float* __restrict__ bn)
{
    if (blockIdx.x == 1152) {
        if (threadIdx.x < 64) {
            const int c = threadIdx.x;
            const float inv = gamma[c] * rsqrtf(var[c] + 1e-3f);
            bn[c] = inv;
            bn[64 + c] = beta[c] - mean[c] * inv;
        }
        return;
    }
    const int i = blockIdx.x * 256 + threadIdx.x;   // < 294912
    const int j  = i & 7;
    const int n  = (i >> 3) & 255;
    const int kg = (i >> 11) & 3;
    const int s  = i >> 13;            // 0..35
    const int sub = s % 18;
    const float* W = (s >= 18) ? Wh : Wx;
    const int k5 = sub * 32 + kg * 8 + j;
    const int c = k5 & 63, q = k5 >> 6;
    const int kx = q % 3, ky = q / 3;
    Wc[i] = f2h(W[(size_t)((ky * 3 + kx) * 64 + c) * 256 + n]);
}

// B-frag register loads: chunk ci, this lane's pair (nf=0 at boff, nf=1 at +128)
#define BLOAD(slot, ci) {                                                     \
    const unsigned short* _p = Wc + (size_t)(ci) * CHUNK + boff;              \
    bp[slot][0] = *(const half8*)_p;                                          \
    bp[slot][1] = *(const half8*)(_p + 128);                                  \
}

// 18-chunk conv pass (step kernel), B from reg pipeline.
template<int C0, int CLAST, int AOFF>
__device__ __forceinline__ void conv_pass18(
    const unsigned short* __restrict__ Wc, const int boff,
    half8 (&bp)[NB][2],
    const unsigned short* abase,
    f32x4 acc[2][2])
{
    #pragma unroll
    for (int sub = 0; sub < 18; ++sub) {
        const int ci = C0 + sub;
        if (ci + PF <= CLAST) BLOAD((ci + PF) % NB, ci + PF)

        const int ky = sub / 6, kx = (sub / 2) % 3, cb = sub & 1;
        const half8 b0 = bp[ci % NB][0];
        const half8 b1 = bp[ci % NB][1];
        const unsigned short* at = abase + AOFF + (ky * 34 + kx) * APAD + cb * 32;
        const half8 a0 = *(const half8*)(at);
        const half8 a1 = *(const half8*)(at + 16 * APAD);
        acc[0][0] = __builtin_amdgcn_mfma_f32_16x16x32_f16(a0, b0, acc[0][0], 0, 0, 0);
        acc[0][1] = __builtin_amdgcn_mfma_f32_16x16x32_f16(a0, b1, acc[0][1], 0, 0, 0);
        acc[1][0] = __builtin_amdgcn_mfma_f32_16x16x32_f16(a1, b0, acc[1][0], 0, 0, 0);
        acc[1][1] = __builtin_amdgcn_mfma_f32_16x16x32_f16(a1, b1, acc[1][1], 0, 0, 0);
    }
}

// Hoisted x-conv, 2 rows/block: xg = conv(x_t,Wx)+bias, fp16, blocked layout:
// record vi = ((((n*16+t)*64+y)*2+xh)*8+w)*64+lane -> 16 shorts [mfc][nf][j].
// Grid 1024 = (n,t,y2), XCD-swizzled. 8 waves; wave w owns ch [w*32,w*32+32).
__global__ __launch_bounds__(512) void xconv_kernel(
    const float* __restrict__ x,
    const unsigned short* __restrict__ Wc,
    const float* __restrict__ bias,
    unsigned short* __restrict__ xg)
{
    const int bid0 = blockIdx.x;
    const int bid = (bid0 & 7) * 128 + (bid0 >> 3);  // bijective: XCD owns (t,y)-slabs
    const int y0 = (bid & 31) * 2;
    const int t  = (bid >> 5) & 15;
    const int n  = bid >> 9;
    const int tid = threadIdx.x, lane = tid & 63, w = tid >> 6;
    const int p0 = lane & 15, g = lane >> 4;

    // A tile only: [4 rows][66 cols][APAD] fp16 = 38016 B
    __shared__ __align__(16) unsigned short smem[4 * 66 * APAD];

    const int boff = g * 2048 + (w * 32 + p0) * 8;

    // B prologue: chunks 0..PF-1 into regs (latency hides under A-staging)
    half8 bp[NB][2];
    #pragma unroll
    for (int sc = 0; sc < PF; ++sc) BLOAD(sc, sc)

    // stage A tile: rows y0-1..y0+2
    const float* __restrict__ xt = x + (size_t)(n * TT + t) * 4096 * 64;
    for (int idx = tid; idx < 4 * 66 * 8; idx += 512) {
        const int cg  = idx & 7;
        const int col = (idx >> 3) % 66;
        const int r   = (idx >> 3) / 66;
        const int gy = y0 + r - 1;
        const int gx = col - 1;
        const bool ok = ((unsigned)gy < 64u) && ((unsigned)gx < 64u);
        float4 v0 = make_float4(0.f, 0.f, 0.f, 0.f), v1 = v0;
        if (ok) {
            const float* p = xt + (size_t)(gy * 64 + gx) * 64 + cg * 8;
            v0 = *(const float4*)p;
            v1 = *(const float4*)(p + 4);
        }
        us4 h0, h1;
        h0.x = f2h(v0.x); h0.y = f2h(v0.y); h0.z = f2h(v0.z); h0.w = f2h(v0.w);
        h1.x = f2h(v1.x); h1.y = f2h(v1.y); h1.z = f2h(v1.z); h1.w = f2h(v1.w);
        const int ebase = (r * 66 + col) * APAD + cg * 8;
        *(us4*)&smem[ebase]     = h0;
        *(us4*)&smem[ebase + 4] = h1;
    }
    __syncthreads();

    const unsigned short* abase = smem + p0 * APAD + g * 8;

    // K-loop: 18 chunks (Wx), 8 m-frags (2 rows x 64 px), B from regs
    f32x4 acc[8][2] = {};
    #pragma unroll
    for (int sub = 0; sub < 18; ++sub) {
        if (sub + PF < 18) BLOAD((sub + PF) % NB, sub + PF)

        const int ky = sub / 6, kx = (sub / 2) % 3, cb = sub & 1;
        const half8 b0 = bp[sub % NB][0];
        const half8 b1 = bp[sub % NB][1];
        #pragma unroll
        for (int mf = 0; mf < 8; ++mf) {
            const int r = mf >> 2, cq = mf & 3;
            const half8 a = *(const half8*)(abase
                + ((r + ky) * 66 + cq * 16 + kx) * APAD + cb * 32);
            acc[mf][0] = __builtin_amdgcn_mfma_f32_16x16x32_f16(a, b0, acc[mf][0], 0, 0, 0);
            acc[mf][1] = __builtin_amdgcn_mfma_f32_16x16x32_f16(a, b1, acc[mf][1], 0, 0, 0);
        }
    }

    // packed xg store: 4 records (r, xh) of 32 B per lane
    const float bv0 = bias[w * 32 + p0];
    const float bv1 = bias[w * 32 + 16 + p0];
    #pragma unroll
    for (int r = 0; r < 2; ++r)
        #pragma unroll
        for (int xh2 = 0; xh2 < 2; ++xh2) {
            unsigned short os[16];
            #pragma unroll
            for (int mfc = 0; mfc < 2; ++mfc)
                #pragma unroll
                for (int nf = 0; nf < 2; ++nf)
                    #pragma unroll
                    for (int j = 0; j < 4; ++j)
                        os[mfc * 8 + nf * 4 + j] =
                            f2h(acc[r * 4 + xh2 * 2 + mfc][nf][j] + (nf ? bv1 : bv0));
            const size_t vi = ((((size_t)(n * TT + t) * 64 + (y0 + r)) * 2 + xh2) * 8 + w) * 64 + lane;
            unsigned short* dst = xg + vi * 16;
            *(uint4*)dst       = *(uint4*)&os[0];
            *(uint4*)(dst + 8) = *(uint4*)&os[8];
        }
}

// Per-timestep kernel. FUSED=1: full x+h conv (ws fallback). FUSED=0: h-conv + xg.
// Block = (n,y,xhalf): 32 px x 256 ch, 8 waves.
template<int FUSED>
__global__ __launch_bounds__(512) void convstep_kernel(
    const float* __restrict__ x,
    const unsigned short* __restrict__ hb,
    const unsigned short* __restrict__ Wc,
    const float* __restrict__ bias,
    const unsigned short* __restrict__ xg,
    float* __restrict__ cbuf,
    unsigned short* __restrict__ ho,
    const float* __restrict__ bn,
    float* __restrict__ out,
    const int t)
{
    const int bid0 = blockIdx.x;
    const int bid = (bid0 & 7) * 32 + (bid0 >> 3);   // bijective XCD swizzle
    const int xh = bid & 1;
    const int y  = (bid >> 1) & 63;
    const int n  = bid >> 7;
    const int tid = threadIdx.x;
    const int lane = tid & 63;
    const int w = tid >> 6;
    const int p0 = lane & 15;
    const int g  = lane >> 4;

    // smem: A tiles; overlaid by gate buffer [4][32][68] f32 = 34816 B after K-loop
    constexpr int SMEM_SHORTS = FUSED ? (2 * A_TILE) : 17408;   // FUSED0: 34816 B
    __shared__ __align__(16) unsigned short smem[SMEM_SHORTS];

    const int boff = g * 2048 + (w * 32 + p0) * 8;

    // packed xg prefetch: one 32B record per lane
    unsigned short xs[16];
    if (!FUSED) {
        const size_t vi = ((((size_t)(n * TT + t) * 64 + y) * 2 + xh) * 8 + w) * 64 + lane;
        const uint4* xp = (const uint4*)(xg + vi * 16);
        *(uint4*)&xs[0] = xp[0];
        *(uint4*)&xs[8] = xp[1];
    }

    // B prologue into regs (latency hides under A-staging)
    constexpr int C0 = FUSED ? 0 : 18;
    half8 bp[NB][2];
    #pragma unroll
    for (int sc = 0; sc < PF; ++sc) BLOAD((C0 + sc) % NB, C0 + sc)

    // ---- stage A tiles: FUSED: x(tile0) + h(tile1); else h(tile0) ----
    constexpr int NTILE = FUSED ? 2 : 1;
    const float* __restrict__ xt = x + (size_t)(n * TT + t) * 4096 * 64;
    const size_t hbase = (size_t)n * 4096 * 64;
    for (int idx = tid; idx < NTILE * 3 * 34 * 8; idx += 512) {
        const int cg  = idx & 7;
        const int col = (idx >> 3) % 34;
        const int i3  = (idx >> 3) / 34;
        const int r   = i3 % 3;
        const int src = i3 / 3;
        const int gy = y + r - 1;
        const int gx = xh * 32 + col - 1;
        const bool ok = ((unsigned)gy < 64u) && ((unsigned)gx < 64u);
        const int ebase = (r * 34 + col) * APAD + cg * 8;
        if (FUSED && src == 0) {
            float4 v0 = make_float4(0.f, 0.f, 0.f, 0.f), v1 = v0;
            if (ok) {
                const float* p = xt + (size_t)(gy * 64 + gx) * 64 + cg * 8;
                v0 = *(const float4*)p;
                v1 = *(const float4*)(p + 4);
            }
            us4 h0, h1;
            h0.x = f2h(v0.x); h0.y = f2h(v0.y); h0.z = f2h(v0.z); h0.w = f2h(v0.w);
            h1.x = f2h(v1.x); h1.y = f2h(v1.y); h1.z = f2h(v1.z); h1.w = f2h(v1.w);
            *(us4*)&smem[ebase]     = h0;
            *(us4*)&smem[ebase + 4] = h1;
        } else {
            uint4 v = make_uint4(0u, 0u, 0u, 0u);
            if (ok) v = *(const uint4*)(hb + hbase + (size_t)(gy * 64 + gx) * 64 + cg * 8);
            *(uint4*)&smem[(FUSED ? A_TILE : 0) + ebase] = v;
        }
    }
    __syncthreads();

    // ---- K-loop (B from reg pipeline, compiler-managed waits) ----
    const unsigned short* abase = smem + p0 * APAD + g * 8;

    f32x4 acc[2][2] = {};
    if (FUSED) {
        conv_pass18<0, 35, 0>(Wc, boff, bp, abase, acc);
        conv_pass18<18, 35, A_TILE>(Wc, boff, bp, abase, acc);
    } else {
        conv_pass18<18, 35, 0>(Wc, boff, bp, abase, acc);
    }

    // ---- gates -> LDS gate buffer (overlay A region) ----
    __syncthreads();
    float* gbuf = (float*)smem;            // [4][32][68] f32 = 34816 B
    const int gate = w >> 1;
    const int chalf = (w & 1) * 32;

    float bv[2];
    bv[0] = bias[w * 32 + p0];
    bv[1] = bias[w * 32 + 16 + p0];

    #pragma unroll
    for (int mf = 0; mf < 2; ++mf)
        #pragma unroll
        for (int nf = 0; nf < 2; ++nf)
            #pragma unroll
            for (int j = 0; j < 4; ++j) {
                float v = acc[mf][nf][j] + (FUSED ? bv[nf] : h2f(xs[mf * 8 + nf * 4 + j]));
                v = (gate == 2) ? tanhf(v) : hsig(v);   // gate order i,f,g,o
                const int px = mf * 16 + g * 4 + j;
                gbuf[(gate * 32 + px) * 68 + chalf + nf * 16 + p0] = v;
            }
    __syncthreads();

    // ---- state update + BN output ----
    const int p  = tid >> 4;
    const int c4 = (tid & 15) * 4;
    const float4 iv = *(const float4*)&gbuf[(0 * 32 + p) * 68 + c4];
    const float4 fv = *(const float4*)&gbuf[(1 * 32 + p) * 68 + c4];
    const float4 gv = *(const float4*)&gbuf[(2 * 32 + p) * 68 + c4];
    const float4 ov = *(const float4*)&gbuf[(3 * 32 + p) * 68 + c4];
    const size_t gpix = (size_t)((n * 64 + y) * 64 + xh * 32 + p);
    const size_t sb = gpix * 64 + c4;
    const float4 cold = *(const float4*)&cbuf[sb];
    const float4 scv  = *(const float4*)&bn[c4];
    const float4 shv  = *(const float4*)&bn[64 + c4];

    const float ivv[4] = {iv.x, iv.y, iv.z, iv.w};
    const float fvv[4] = {fv.x, fv.y, fv.z, fv.w};
    const float gvv[4] = {gv.x, gv.y, gv.z, gv.w};
    const float ovv[4] = {ov.x, ov.y, ov.z, ov.w};
    const float cov[4] = {cold.x, cold.y, cold.z, cold.w};
    const float scc[4] = {scv.x, scv.y, scv.z, scv.w};
    const float shh[4] = {shv.x, shv.y, shv.z, shv.w};

    float cnew[4], obuf[4];
    us4 hh;
    unsigned short* hhp = (unsigned short*)&hh;
    #pragma unroll
    for (int j = 0; j < 4; ++j) {
        const float cn = fvv[j] * cov[j] + ivv[j] * gvv[j];
        const float hn = ovv[j] * tanhf(cn);
        cnew[j] = cn;
        hhp[j] = f2h(hn);
        obuf[j] = hn * scc[j] + shh[j];
    }
    *(float4*)&cbuf[sb] = *(float4*)&cnew[0];
    *(us4*)&ho[sb]      = hh;
    const size_t ob = ((size_t)((n * TT + t) * 4096 + y * 64 + xh * 32 + p)) * 64 + c4;
    *(float4*)&out[ob] = *(float4*)&obuf[0];
}

extern "C" void kernel_launch(void* const* d_in, const int* in_sizes, int n_in,
                              void* d_out, int out_size, void* d_ws, size_t ws_size,
                              hipStream_t stream) {
    const float* x     = (const float*)d_in[0];
    const float* Wx    = (const float*)d_in[1];
    const float* Wh    = (const float*)d_in[2];
    const float* b     = (const float*)d_in[3];
    const float* gamma = (const float*)d_in[4];
    const float* beta  = (const float*)d_in[5];
    const float* mean  = (const float*)d_in[6];
    const float* var   = (const float*)d_in[7];
    float* out = (float*)d_out;
    char* ws = (char*)d_ws;

    unsigned short* Wc   = (unsigned short*)(ws);            // 589,824 B
    float*          bn   = (float*)(ws + 589824);            // 512 B
    unsigned short* hA   = (unsigned short*)(ws + 590336);   // 1 MB fp16
    float*          cbuf = (float*)(ws + 1638912);           // 2 MB fp32
    unsigned short* hB   = (unsigned short*)(ws + 3736064);  // 1 MB fp16
    unsigned short* xg   = (unsigned short*)(ws + 4784640);  // 67,108,864 B
    const size_t NEED = 4784640ull + 67108864ull;            // 71,893,504 B

    hipMemsetAsync(ws + 590336, 0, 3145728, stream);         // h0 + c0 = 0
    prep_kernel<<<1153, 256, 0, stream>>>(Wx, Wh, gamma, beta, mean, var, Wc, bn);

    if (ws_size >= NEED) {
        xconv_kernel<<<1024, 512, 0, stream>>>(x, Wc, b, xg);
        for (int t = 0; t < TT; ++t) {
            const bool even = (t & 1) == 0;
            convstep_kernel<0><<<256, 512, 0, stream>>>(
                x, even ? hA : hB, Wc, b, xg, cbuf, even ? hB : hA, bn, out, t);
        }
    } else {
        for (int t = 0; t < TT; ++t) {
            const bool even = (t & 1) == 0;
            convstep_kernel<1><<<256, 512, 0, stream>>>(
                x, even ? hA : hB, Wc, b, xg, cbuf, even ? hB : hA, bn, out, t);
        }
    }
}